// Round 4
// baseline (1617.680 us; speedup 1.0000x reference)
//
#include <hip/hip_runtime.h>

#define N_PIX 1024      // 32*32 pixels per image
#define BATCH 32
#define CCH 256         // channels == code dim
#define KCODES 4096
#define NROWS 32768     // BATCH * N_PIX

#define RPB 16          // rows per block (ONE wave per block)
#define KTILE 256       // codes per k-tile; lane l computes codes 4l..4l+3
#define DCH 4           // channels per LDS chunk
#define NCHUNK ((KCODES / KTILE) * (CCH / DCH))   // 16 * 64 = 1024

// ---------------- kernel 0: e_sq[k] = sum_c emb[k][c]^2 ----------------
__global__ __launch_bounds__(256) void esq_kernel(const float* __restrict__ emb,
                                                  float* __restrict__ esq) {
    const int t = threadIdx.x;
    const int w = t >> 6, l = t & 63;
    const int k = blockIdx.x * 4 + w;
    const float4 v = *(const float4*)(emb + (size_t)k * CCH + l * 4);
    float s = v.x * v.x + v.y * v.y + v.z * v.z + v.w * v.w;
#pragma unroll
    for (int off = 32; off > 0; off >>= 1) s += __shfl_down(s, off);
    if (l == 0) esq[k] = s;
}

// ---------------- kernel 1: fused distance + argmin (1 wave / block) ----------------
// score(n,k) = esq[k] - 2*dot(x_n, e_k)   (x_sq dropped: constant per row)
// x rows are uniform functions of blockIdx -> scalar (SMEM) loads, zero LDS.
// emb chunk in private 2x4KB LDS dbuf; staging: lane l stages codes {64j+l}
// (b32 column writes, conflict-free); compute: lane l reads codes 4l..4l+3
// (contiguous ds_read_b128, conflict-free). No __syncthreads anywhere:
// one wave per block, DS ops are in-order within a wave.
__global__ __launch_bounds__(64, 3) void argmin_kernel(
    const float* __restrict__ x, const float* __restrict__ emb,
    const float* __restrict__ esq, int* __restrict__ bidx)
{
    __shared__ float es[2][DCH * KTILE];   // 2 x 4 KB

    const int l = threadIdx.x;             // lane 0..63
    const int n0 = blockIdx.x * RPB;
    const int b = n0 >> 10;
    const int p0 = n0 & (N_PIX - 1);
    const float* xb = x + (size_t)b * CCH * N_PIX + p0;   // wave-uniform base

    float best[RPB];
    int bk[RPB];
#pragma unroll
    for (int r = 0; r < RPB; ++r) { best[r] = 3.4e38f; bk[r] = 0; }

    float acc[RPB][4];
#pragma unroll
    for (int r = 0; r < RPB; ++r)
#pragma unroll
        for (int j = 0; j < 4; ++j) acc[r][j] = 0.f;

    // prologue: stage chunk 0 (kt=0, c0=0) into es[0]
    {
        const float4 s0 = *(const float4*)(emb + (size_t)(l) * CCH);
        const float4 s1 = *(const float4*)(emb + (size_t)(64 + l) * CCH);
        const float4 s2 = *(const float4*)(emb + (size_t)(128 + l) * CCH);
        const float4 s3 = *(const float4*)(emb + (size_t)(192 + l) * CCH);
#pragma unroll
        for (int c = 0; c < DCH; ++c) {
            es[0][c * KTILE + l]       = ((const float*)&s0)[c];
            es[0][c * KTILE + 64 + l]  = ((const float*)&s1)[c];
            es[0][c * KTILE + 128 + l] = ((const float*)&s2)[c];
            es[0][c * KTILE + 192 + l] = ((const float*)&s3)[c];
        }
    }

#define CHUNK_BODY(RD, WR, CH)                                                 \
    {                                                                          \
        const int kt = (CH) >> 6;                                              \
        const int c0 = ((CH) & 63) * DCH;                                      \
        float4 st0, st1, st2, st3;                                             \
        const bool do_stage = (CH) != NCHUNK - 1;                              \
        if (do_stage) {                                                        \
            const int nkt = ((CH) + 1) >> 6;                                   \
            const int nc0 = (((CH) + 1) & 63) * DCH;                           \
            const float* eb = emb + (size_t)(nkt * KTILE) * CCH + nc0;         \
            st0 = *(const float4*)(eb + (size_t)(l) * CCH);                    \
            st1 = *(const float4*)(eb + (size_t)(64 + l) * CCH);               \
            st2 = *(const float4*)(eb + (size_t)(128 + l) * CCH);              \
            st3 = *(const float4*)(eb + (size_t)(192 + l) * CCH);              \
        }                                                                      \
        float xv[DCH][RPB];                                                    \
        _Pragma("unroll") for (int c = 0; c < DCH; ++c) {                      \
            const float* xrow = xb + (size_t)(c0 + c) * N_PIX;                 \
            _Pragma("unroll") for (int r = 0; r < RPB; ++r)                    \
                xv[c][r] = xrow[r];   /* uniform -> scalar loads */            \
        }                                                                      \
        _Pragma("unroll") for (int c = 0; c < DCH; ++c) {                      \
            const float4 ev = *(const float4*)(&es[RD][c * KTILE + 4 * l]);    \
            _Pragma("unroll") for (int r = 0; r < RPB; ++r) {                  \
                acc[r][0] = fmaf(xv[c][r], ev.x, acc[r][0]);                   \
                acc[r][1] = fmaf(xv[c][r], ev.y, acc[r][1]);                   \
                acc[r][2] = fmaf(xv[c][r], ev.z, acc[r][2]);                   \
                acc[r][3] = fmaf(xv[c][r], ev.w, acc[r][3]);                   \
            }                                                                  \
        }                                                                      \
        if (do_stage) {                                                        \
            _Pragma("unroll") for (int c = 0; c < DCH; ++c) {                  \
                es[WR][c * KTILE + l]       = ((const float*)&st0)[c];         \
                es[WR][c * KTILE + 64 + l]  = ((const float*)&st1)[c];         \
                es[WR][c * KTILE + 128 + l] = ((const float*)&st2)[c];         \
                es[WR][c * KTILE + 192 + l] = ((const float*)&st3)[c];         \
            }                                                                  \
        }                                                                      \
        if (((CH) & 63) == 63) {                                               \
            const float4 q = *(const float4*)(esq + kt * KTILE + 4 * l);       \
            const int kb = kt * KTILE + 4 * l;                                 \
            _Pragma("unroll") for (int r = 0; r < RPB; ++r) {                  \
                float s;                                                       \
                s = fmaf(-2.f, acc[r][0], q.x);                                \
                if (s < best[r]) { best[r] = s; bk[r] = kb; }                  \
                s = fmaf(-2.f, acc[r][1], q.y);                                \
                if (s < best[r]) { best[r] = s; bk[r] = kb + 1; }              \
                s = fmaf(-2.f, acc[r][2], q.z);                                \
                if (s < best[r]) { best[r] = s; bk[r] = kb + 2; }              \
                s = fmaf(-2.f, acc[r][3], q.w);                                \
                if (s < best[r]) { best[r] = s; bk[r] = kb + 3; }              \
                acc[r][0] = 0.f; acc[r][1] = 0.f;                              \
                acc[r][2] = 0.f; acc[r][3] = 0.f;                              \
            }                                                                  \
        }                                                                      \
    }

    for (int ch = 0; ch < NCHUNK; ch += 2) {
        CHUNK_BODY(0, 1, ch);
        CHUNK_BODY(1, 0, ch + 1);
    }
#undef CHUNK_BODY

    // cross-lane merge per row (codes are disjoint across lanes)
#pragma unroll
    for (int r = 0; r < RPB; ++r) {
        float bv = best[r]; int bi = bk[r];
#pragma unroll
        for (int off = 32; off > 0; off >>= 1) {
            const float ov = __shfl_xor(bv, off, 64);
            const int   oi = __shfl_xor(bi, off, 64);
            if (ov < bv || (ov == bv && oi < bi)) { bv = ov; bi = oi; }
        }
        if (l == 0) bidx[n0 + r] = bi;
    }
}

// ---------------- kernel 2: gather + write oup (NCHW) + loss partials ----------------
__global__ __launch_bounds__(256) void gather_kernel(
    const float* __restrict__ x, const float* __restrict__ emb,
    const int* __restrict__ bidx, float* __restrict__ oup,
    float* __restrict__ partial)
{
    __shared__ int sidx[64];
    __shared__ float red[256];
    const int t = threadIdx.x;
    const int n0 = blockIdx.x * 64;
    const int b = n0 >> 10;
    const int pixbase = n0 & (N_PIX - 1);
    if (t < 64) sidx[t] = bidx[n0 + t];
    __syncthreads();
    const int pl = t & 63;    // pixel within tile (contiguous lanes -> coalesced x/oup)
    const int w = t >> 6;     // c quadrant
    const int k = sidx[pl];
    const float* xbp = x + (size_t)b * CCH * N_PIX + pixbase + pl;
    float* ob = oup + (size_t)b * CCH * N_PIX + pixbase + pl;
    const float* ek = emb + (size_t)k * CCH + w * 64;
    float lsum = 0.f;
#pragma unroll 4
    for (int cc = 0; cc < 16; ++cc) {
        const float4 e4 = *(const float4*)(ek + cc * 4);
        const float er[4] = {e4.x, e4.y, e4.z, e4.w};
#pragma unroll
        for (int j = 0; j < 4; ++j) {
            const size_t off = (size_t)(w * 64 + cc * 4 + j) * N_PIX;
            const float xv = xbp[off];
            ob[off] = er[j];
            const float d = xv - er[j];
            lsum = fmaf(d, d, lsum);
        }
    }
    red[t] = lsum;
    __syncthreads();
#pragma unroll
    for (int s = 128; s > 0; s >>= 1) {
        if (t < s) red[t] += red[t + s];
        __syncthreads();
    }
    if (t == 0) partial[blockIdx.x] = red[0];
}

// ---------------- kernel 3: finalize losses ----------------
__global__ __launch_bounds__(256) void finalize_kernel(const float* __restrict__ partial,
                                                       float* __restrict__ out_losses) {
    __shared__ float red[256];
    const int t = threadIdx.x;
    red[t] = partial[t] + partial[t + 256];
    __syncthreads();
    for (int s = 128; s > 0; s >>= 1) {
        if (t < s) red[t] += red[t + s];
        __syncthreads();
    }
    if (t == 0) {
        const float loss = red[0] * (1.0f / 8388608.0f);
        out_losses[0] = loss;   // dictionary_loss
        out_losses[1] = loss;   // commitment_loss (numerically identical)
    }
}

extern "C" void kernel_launch(void* const* d_in, const int* in_sizes, int n_in,
                              void* d_out, int out_size, void* d_ws, size_t ws_size,
                              hipStream_t stream) {
    const float* x = (const float*)d_in[0];
    const float* emb = (const float*)d_in[1];
    float* out = (float*)d_out;

    // workspace layout
    float* esq = (float*)d_ws;                                  // 4096 f32 (16 KB)
    int* bidx = (int*)((char*)d_ws + 16384);                    // 32768 i32 (128 KB)
    float* partial = (float*)((char*)d_ws + 16384 + 131072);    // 512 f32 (2 KB)

    esq_kernel<<<KCODES / 4, 256, 0, stream>>>(emb, esq);
    argmin_kernel<<<NROWS / RPB, 64, 0, stream>>>(x, emb, esq, bidx);
    gather_kernel<<<NROWS / 64, 256, 0, stream>>>(x, emb, bidx, out, partial);
    finalize_kernel<<<1, 256, 0, stream>>>(partial, out + 8388608);
}

// Round 5
// 1450.579 us; speedup vs baseline: 1.1152x; 1.1152x over previous
//
#include <hip/hip_runtime.h>

#define N_PIX 1024      // 32*32 pixels per image
#define BATCH 32
#define CCH 256         // channels == code dim
#define KCODES 4096
#define NROWS 32768     // BATCH * N_PIX
#define DELTA 0.0625f   // rescore margin (error bound ~0.005 worst case)

typedef __attribute__((ext_vector_type(8))) short bf16x8;
typedef __attribute__((ext_vector_type(4))) float f32x4;

// ---- ws layout (bytes) ----
#define OFF_ESQ   0u
#define OFF_BIDX  16384u
#define OFF_FLAGS 147456u
#define OFF_PART  278528u
#define OFF_TOP2  524288u                    // 64 chunks x 32768 rows x float4 = 32 MB
#define OFF_A     34078720u                  // 8 kt x 32768 x 128 B = 32 MB
#define OFF_B     67633152u                  // 8 kt x 4096 x 128 B = 4 MB
#define WS_NEEDED 71827456u

// round-to-nearest-even fp32 -> bf16 bits
__device__ __forceinline__ unsigned short f2bf(float v) {
    unsigned u = __float_as_uint(v);
    return (unsigned short)((u + 0x7FFFu + ((u >> 16) & 1u)) >> 16);
}
__device__ __forceinline__ float bf2f(unsigned short h) {
    return __uint_as_float(((unsigned)h) << 16);
}

__device__ __forceinline__ void gload_lds16(const void* g, void* l) {
    __builtin_amdgcn_global_load_lds(
        (const __attribute__((address_space(1))) unsigned int*)g,
        (__attribute__((address_space(3))) unsigned int*)l, 16, 0, 0);
}

// ---------------- kernel 0: e_sq[k] = sum_c emb[k][c]^2 (exact fp32) ----------------
__global__ __launch_bounds__(256) void esq_kernel(const float* __restrict__ emb,
                                                  float* __restrict__ esq) {
    const int t = threadIdx.x;
    const int w = t >> 6, l = t & 63;
    const int k = blockIdx.x * 4 + w;
    const float4 v = *(const float4*)(emb + (size_t)k * CCH + l * 4);
    float s = v.x * v.x + v.y * v.y + v.z * v.z + v.w * v.w;
#pragma unroll
    for (int off = 32; off > 0; off >>= 1) s += __shfl_down(s, off);
    if (l == 0) esq[k] = s;
}

// ---------------- conv_x: x fp32 NCHW -> pre-swizzled bf16 hi/lo tiles ----------------
// A[kt][m][128B]: kt 0-3 = hi(channels kt*64..+64), kt 4-7 = lo.
// within 128-row tile: byte(row, granule g) = (row*128 + g*16) ^ ((row&7)<<4)
__global__ __launch_bounds__(256) void conv_x_kernel(const float* __restrict__ x,
                                                     char* __restrict__ A) {
    const int t = threadIdx.x;
    const int m = blockIdx.x * 64 + (t & 63);
    const int kt = t >> 6;                       // 0..3
    const int b = m >> 10, p = m & 1023;
    const float* src = x + ((size_t)b * CCH + kt * 64) * N_PIX + p;
    char* hi_base = A + (size_t)kt * (NROWS * 128) + (size_t)(m >> 7) * 16384;
    char* lo_base = hi_base + (size_t)4 * (NROWS * 128);
    const int row = m & 127;
    const int swz = (row & 7) << 4;
#pragma unroll
    for (int g = 0; g < 8; ++g) {
        unsigned hv[4], lv[4];
#pragma unroll
        for (int e2 = 0; e2 < 4; ++e2) {
            const float v0 = src[(size_t)(g * 8 + e2 * 2 + 0) * N_PIX];
            const float v1 = src[(size_t)(g * 8 + e2 * 2 + 1) * N_PIX];
            const unsigned short h0 = f2bf(v0), h1 = f2bf(v1);
            const unsigned short l0 = f2bf(v0 - bf2f(h0)), l1 = f2bf(v1 - bf2f(h1));
            hv[e2] = (unsigned)h0 | ((unsigned)h1 << 16);
            lv[e2] = (unsigned)l0 | ((unsigned)l1 << 16);
        }
        const int byte = (row * 128 + g * 16) ^ swz;
        *(uint4*)(hi_base + byte) = make_uint4(hv[0], hv[1], hv[2], hv[3]);
        *(uint4*)(lo_base + byte) = make_uint4(lv[0], lv[1], lv[2], lv[3]);
    }
}

// ---------------- conv_e: embedding fp32 -> pre-swizzled bf16 hi/lo tiles ----------------
__global__ __launch_bounds__(256) void conv_e_kernel(const float* __restrict__ emb,
                                                     char* __restrict__ B) {
    const int t = threadIdx.x;
    const int n = blockIdx.x * 64 + (t & 63);
    const int kt = t >> 6;
    const float* src = emb + (size_t)n * CCH + kt * 64;
    char* hi_base = B + (size_t)kt * (KCODES * 128) + (size_t)(n >> 7) * 16384;
    char* lo_base = hi_base + (size_t)4 * (KCODES * 128);
    const int row = n & 127;
    const int swz = (row & 7) << 4;
#pragma unroll
    for (int g = 0; g < 8; ++g) {
        const float4 a = *(const float4*)(src + g * 8);
        const float4 c = *(const float4*)(src + g * 8 + 4);
        const float vr[8] = {a.x, a.y, a.z, a.w, c.x, c.y, c.z, c.w};
        unsigned hv[4], lv[4];
#pragma unroll
        for (int e2 = 0; e2 < 4; ++e2) {
            const unsigned short h0 = f2bf(vr[e2 * 2]), h1 = f2bf(vr[e2 * 2 + 1]);
            const unsigned short l0 = f2bf(vr[e2 * 2] - bf2f(h0));
            const unsigned short l1 = f2bf(vr[e2 * 2 + 1] - bf2f(h1));
            hv[e2] = (unsigned)h0 | ((unsigned)h1 << 16);
            lv[e2] = (unsigned)l0 | ((unsigned)l1 << 16);
        }
        const int byte = (row * 128 + g * 16) ^ swz;
        *(uint4*)(hi_base + byte) = make_uint4(hv[0], hv[1], hv[2], hv[3]);
        *(uint4*)(lo_base + byte) = make_uint4(lv[0], lv[1], lv[2], lv[3]);
    }
}

// ---------------- mfma_top2: 128x128 tile GEMM (K=12 tile-pairs of 64) + fused top-2 ----------------
// dot(m,n) = xh.eh + xl.eh + xh.el ; score = esq[n] - 2*dot
// 4 waves in 2x2; wave owns 64x64; 16x16x32 bf16 MFMA, 4x4 frags.
__global__ __launch_bounds__(256) void mfma_top2_kernel(
    const char* __restrict__ Ag, const char* __restrict__ Bg,
    const float* __restrict__ esq, float4* __restrict__ top2)
{
    __shared__ char lds[32768];   // A tile 16K | B tile 16K
    const int t = threadIdx.x;
    const int w = t >> 6, l = t & 63;
    const int nb = blockIdx.x;    // 0..31 code-block
    const int mb = blockIdx.y;    // 0..255 row-block
    const int lh = l >> 4, ll = l & 15;

    f32x4 acc[4][4];
#pragma unroll
    for (int i = 0; i < 4; ++i)
#pragma unroll
        for (int j = 0; j < 4; ++j) acc[i][j] = 0.f;

    const int pa[12] = {0, 1, 2, 3, 4, 5, 6, 7, 0, 1, 2, 3};
    const int pb[12] = {0, 1, 2, 3, 0, 1, 2, 3, 4, 5, 6, 7};

    for (int pp = 0; pp < 12; ++pp) {
        __syncthreads();
        const char* At = Ag + ((size_t)pa[pp] * NROWS + (size_t)mb * 128) * 128;
        const char* Bt = Bg + ((size_t)pb[pp] * KCODES + (size_t)nb * 128) * 128;
#pragma unroll
        for (int i = 0; i < 4; ++i) {
            const int g = i * 256 + t;
            gload_lds16(At + g * 16, lds + g * 16);
            gload_lds16(Bt + g * 16, lds + 16384 + g * 16);
        }
        asm volatile("s_waitcnt vmcnt(0)" ::: "memory");
        __syncthreads();

        const int mbase = (w >> 1) * 64;
        const int nbase = (w & 1) * 64;
#pragma unroll
        for (int ks = 0; ks < 2; ++ks) {
            bf16x8 af[4], bfr[4];
#pragma unroll
            for (int i = 0; i < 4; ++i) {
                const int ar = mbase + i * 16 + ll;
                af[i] = *(const bf16x8*)(lds + ((ar * 128 + ks * 64 + lh * 16) ^ ((ar & 7) << 4)));
                const int br = nbase + i * 16 + ll;
                bfr[i] = *(const bf16x8*)(lds + 16384 + ((br * 128 + ks * 64 + lh * 16) ^ ((br & 7) << 4)));
            }
#pragma unroll
            for (int i = 0; i < 4; ++i)
#pragma unroll
                for (int j = 0; j < 4; ++j)
                    acc[i][j] = __builtin_amdgcn_mfma_f32_16x16x32_bf16(af[i], bfr[j], acc[i][j], 0, 0, 0);
        }
    }

    // epilogue: per-row top2 over this wave's 64 cols.
    // C layout: col = ll, row = lh*4 + reg  (within each 16x16 tile)
    float b1[16], b2[16];
    int k1[16];
#pragma unroll
    for (int q = 0; q < 16; ++q) { b1[q] = 3.4e38f; b2[q] = 3.4e38f; k1[q] = 0; }
    const int colg0 = nb * 128 + (w & 1) * 64 + ll;
#pragma unroll
    for (int j = 0; j < 4; ++j) {
        const int kcol = colg0 + j * 16;
        const float eq = esq[kcol];
#pragma unroll
        for (int i = 0; i < 4; ++i)
#pragma unroll
            for (int r = 0; r < 4; ++r) {
                const float s = fmaf(-2.f, acc[i][j][r], eq);
                const int q = i * 4 + r;
                if (s < b1[q]) { b2[q] = b1[q]; b1[q] = s; k1[q] = kcol; }
                else if (s < b2[q]) { b2[q] = s; }
            }
    }
    // merge the 16 col-lanes (masks 1,2,4,8 stay within the 16-lane group)
#pragma unroll
    for (int msk = 1; msk <= 8; msk <<= 1) {
#pragma unroll
        for (int q = 0; q < 16; ++q) {
            const float ob1 = __shfl_xor(b1[q], msk, 64);
            const int   ok1 = __shfl_xor(k1[q], msk, 64);
            const float ob2 = __shfl_xor(b2[q], msk, 64);
            if (ob1 < b1[q] || (ob1 == b1[q] && ok1 < k1[q])) {
                b2[q] = fminf(b1[q], ob2); b1[q] = ob1; k1[q] = ok1;
            } else {
                b2[q] = fminf(b2[q], ob1);
            }
        }
    }
    if (ll == 0) {
        const size_t cc = (size_t)(nb * 2 + (w & 1)) * NROWS;
#pragma unroll
        for (int q = 0; q < 16; ++q) {
            const int i = q >> 2, r = q & 3;
            const int row = mb * 128 + (w >> 1) * 64 + i * 16 + lh * 4 + r;
            top2[cc + row] = make_float4(b1[q], __int_as_float(k1[q]), b2[q], 0.f);
        }
    }
}

// ---------------- reduce: merge 64 col-chunks per row; flag ambiguous rows ----------------
__global__ __launch_bounds__(256) void reduce_top2_kernel(const float4* __restrict__ top2,
                                                          int* __restrict__ bidx,
                                                          int* __restrict__ flags) {
    const int row = blockIdx.x * 256 + threadIdx.x;
    float b1 = 3.4e38f, b2 = 3.4e38f;
    int k1 = 0x7fffffff;
#pragma unroll 8
    for (int c = 0; c < 64; ++c) {
        const float4 v = top2[(size_t)c * NROWS + row];
        const float ob1 = v.x, ob2 = v.z;
        const int ok1 = __float_as_int(v.y);
        if (ob1 < b1 || (ob1 == b1 && ok1 < k1)) { b2 = fminf(b1, ob2); b1 = ob1; k1 = ok1; }
        else { b2 = fminf(b2, ob1); }
    }
    bidx[row] = k1;
    flags[row] = (b2 - b1 <= DELTA) ? 1 : 0;
}

// ---------------- rescore: exact fp32 argmin for flagged rows ----------------
__global__ __launch_bounds__(256) void rescore_kernel(const float* __restrict__ x,
                                                      const float* __restrict__ emb,
                                                      const float* __restrict__ esq,
                                                      const int* __restrict__ flags,
                                                      int* __restrict__ bidx) {
    const int row = blockIdx.x;
    if (!flags[row]) return;   // uniform across block
    __shared__ float xr[CCH];
    __shared__ float rs[256];
    __shared__ int rk[256];
    const int t = threadIdx.x;
    const int b = row >> 10, p = row & 1023;
    xr[t] = x[((size_t)b * CCH + t) * N_PIX + p];
    __syncthreads();
    float bs = 3.4e38f;
    int bi = 0x7fffffff;
    for (int k = t; k < KCODES; k += 256) {
        const float4* er = (const float4*)(emb + (size_t)k * CCH);
        float dot = 0.f;
#pragma unroll 16
        for (int c = 0; c < 64; ++c) {
            const float4 e4 = er[c];
            const float4 xv = *(const float4*)(xr + c * 4);
            dot = fmaf(xv.x, e4.x, dot);
            dot = fmaf(xv.y, e4.y, dot);
            dot = fmaf(xv.z, e4.z, dot);
            dot = fmaf(xv.w, e4.w, dot);
        }
        const float s = fmaf(-2.f, dot, esq[k]);
        if (s < bs || (s == bs && k < bi)) { bs = s; bi = k; }
    }
    rs[t] = bs; rk[t] = bi;
    __syncthreads();
    for (int s2 = 128; s2 > 0; s2 >>= 1) {
        if (t < s2) {
            if (rs[t + s2] < rs[t] || (rs[t + s2] == rs[t] && rk[t + s2] < rk[t])) {
                rs[t] = rs[t + s2]; rk[t] = rk[t + s2];
            }
        }
        __syncthreads();
    }
    if (t == 0) bidx[row] = rk[0];
}

// ---------------- fallback fp32 argmin (R3 known-good) if ws too small ----------------
#define BROWS 32
#define FKTILE 256
#define FDCH 16
#define FNCHUNK ((KCODES / FKTILE) * (CCH / FDCH))
__global__ __launch_bounds__(256, 2) void argmin_fb_kernel(
    const float* __restrict__ x, const float* __restrict__ emb,
    const float* __restrict__ esq, int* __restrict__ bidx)
{
    __shared__ float xs[CCH * BROWS];
    __shared__ float es[2][FDCH * FKTILE];
    const int t = threadIdx.x;
    const int w = t >> 6;
    const int l = t & 63;
    const int n0 = blockIdx.x * BROWS;
    const int b = n0 >> 10;
    const int pixbase = n0 & (N_PIX - 1);
    const float* xb = x + (size_t)b * CCH * N_PIX + pixbase;
    {
        const int p4 = (t & 7) * 4;
        const int crow = t >> 3;
#pragma unroll
        for (int i = 0; i < 8; ++i) {
            const int c = i * 32 + crow;
            *(float4*)(xs + c * BROWS + p4) = *(const float4*)(xb + (size_t)c * N_PIX + p4);
        }
    }
    {
        const float* src = emb + (size_t)t * CCH;
        const float4 s0 = *(const float4*)(src + 0);
        const float4 s1 = *(const float4*)(src + 4);
        const float4 s2 = *(const float4*)(src + 8);
        const float4 s3 = *(const float4*)(src + 12);
#pragma unroll
        for (int c = 0; c < 4; ++c) {
            es[0][(c + 0) * FKTILE + t] = ((const float*)&s0)[c];
            es[0][(c + 4) * FKTILE + t] = ((const float*)&s1)[c];
            es[0][(c + 8) * FKTILE + t] = ((const float*)&s2)[c];
            es[0][(c + 12) * FKTILE + t] = ((const float*)&s3)[c];
        }
    }
    __syncthreads();
    float best[8]; int bk[8];
#pragma unroll
    for (int r = 0; r < 8; ++r) { best[r] = 3.4e38f; bk[r] = 0; }
    float acc[8][4];
#pragma unroll
    for (int r = 0; r < 8; ++r)
#pragma unroll
        for (int j = 0; j < 4; ++j) acc[r][j] = 0.f;
    for (int chunk = 0; chunk < 64; ++chunk) {   // 16 tiles x 16 chunks merged: reuse simple loop
    }
    // simple non-pipelined loop (correct, ~R2 speed) to keep fallback small:
    for (int kt = 0; kt < KCODES / FKTILE; ++kt) {
        for (int dc = 0; dc < CCH / FDCH; ++dc) {
            __syncthreads();
            {
                const float* src = emb + (size_t)(kt * FKTILE + t) * CCH + dc * FDCH;
#pragma unroll
                for (int c = 0; c < FDCH; ++c) es[0][c * FKTILE + t] = src[c];
            }
            __syncthreads();
            const int c0 = dc * FDCH;
            const float* ep = es[0] + 4 * l;
            const float* xp = xs + c0 * BROWS + w * 8;
#pragma unroll
            for (int c = 0; c < FDCH; ++c) {
                const float4 ev = *(const float4*)(ep + c * FKTILE);
                const float4 xa = *(const float4*)(xp + c * BROWS);
                const float4 xc = *(const float4*)(xp + c * BROWS + 4);
                const float xr8[8] = {xa.x, xa.y, xa.z, xa.w, xc.x, xc.y, xc.z, xc.w};
#pragma unroll
                for (int r = 0; r < 8; ++r) {
                    acc[r][0] = fmaf(xr8[r], ev.x, acc[r][0]);
                    acc[r][1] = fmaf(xr8[r], ev.y, acc[r][1]);
                    acc[r][2] = fmaf(xr8[r], ev.z, acc[r][2]);
                    acc[r][3] = fmaf(xr8[r], ev.w, acc[r][3]);
                }
            }
        }
        const float4 q = *(const float4*)(esq + kt * FKTILE + 4 * l);
        const float qr[4] = {q.x, q.y, q.z, q.w};
#pragma unroll
        for (int r = 0; r < 8; ++r)
#pragma unroll
            for (int j = 0; j < 4; ++j) {
                const float s = fmaf(-2.f, acc[r][j], qr[j]);
                if (s < best[r]) { best[r] = s; bk[r] = kt * FKTILE + 4 * l + j; }
                acc[r][j] = 0.f;
            }
    }
#pragma unroll
    for (int r = 0; r < 8; ++r) {
        float bv = best[r]; int bi = bk[r];
#pragma unroll
        for (int off = 32; off > 0; off >>= 1) {
            const float ov = __shfl_xor(bv, off, 64);
            const int   oi = __shfl_xor(bi, off, 64);
            if (ov < bv || (ov == bv && oi < bi)) { bv = ov; bi = oi; }
        }
        if (l == 0) bidx[n0 + w * 8 + r] = bi;
    }
}

// ---------------- gather + oup + loss partials ----------------
__global__ __launch_bounds__(256) void gather_kernel(
    const float* __restrict__ x, const float* __restrict__ emb,
    const int* __restrict__ bidx, float* __restrict__ oup,
    float* __restrict__ partial)
{
    __shared__ int sidx[64];
    __shared__ float red[256];
    const int t = threadIdx.x;
    const int n0 = blockIdx.x * 64;
    const int b = n0 >> 10;
    const int pixbase = n0 & (N_PIX - 1);
    if (t < 64) sidx[t] = bidx[n0 + t];
    __syncthreads();
    const int pl = t & 63;
    const int w = t >> 6;
    const int k = sidx[pl];
    const float* xbp = x + (size_t)b * CCH * N_PIX + pixbase + pl;
    float* ob = oup + (size_t)b * CCH * N_PIX + pixbase + pl;
    const float* ek = emb + (size_t)k * CCH + w * 64;
    float lsum = 0.f;
#pragma unroll 4
    for (int cc = 0; cc < 16; ++cc) {
        const float4 e4 = *(const float4*)(ek + cc * 4);
        const float er[4] = {e4.x, e4.y, e4.z, e4.w};
#pragma unroll
        for (int j = 0; j < 4; ++j) {
            const size_t off = (size_t)(w * 64 + cc * 4 + j) * N_PIX;
            const float xv = xbp[off];
            ob[off] = er[j];
            const float d = xv - er[j];
            lsum = fmaf(d, d, lsum);
        }
    }
    red[t] = lsum;
    __syncthreads();
#pragma unroll
    for (int s = 128; s > 0; s >>= 1) {
        if (t < s) red[t] += red[t + s];
        __syncthreads();
    }
    if (t == 0) partial[blockIdx.x] = red[0];
}

__global__ __launch_bounds__(256) void finalize_kernel(const float* __restrict__ partial,
                                                       float* __restrict__ out_losses) {
    __shared__ float red[256];
    const int t = threadIdx.x;
    red[t] = partial[t] + partial[t + 256];
    __syncthreads();
    for (int s = 128; s > 0; s >>= 1) {
        if (t < s) red[t] += red[t + s];
        __syncthreads();
    }
    if (t == 0) {
        const float loss = red[0] * (1.0f / 8388608.0f);
        out_losses[0] = loss;
        out_losses[1] = loss;
    }
}

extern "C" void kernel_launch(void* const* d_in, const int* in_sizes, int n_in,
                              void* d_out, int out_size, void* d_ws, size_t ws_size,
                              hipStream_t stream) {
    const float* x = (const float*)d_in[0];
    const float* emb = (const float*)d_in[1];
    float* out = (float*)d_out;

    char* ws = (char*)d_ws;
    float* esq = (float*)(ws + OFF_ESQ);
    int* bidx = (int*)(ws + OFF_BIDX);
    int* flags = (int*)(ws + OFF_FLAGS);
    float* partial = (float*)(ws + OFF_PART);

    esq_kernel<<<KCODES / 4, 256, 0, stream>>>(emb, esq);

    if (ws_size >= (size_t)WS_NEEDED) {
        float4* top2 = (float4*)(ws + OFF_TOP2);
        char* A = ws + OFF_A;
        char* B = ws + OFF_B;
        conv_x_kernel<<<NROWS / 64, 256, 0, stream>>>(x, A);
        conv_e_kernel<<<KCODES / 64, 256, 0, stream>>>(emb, B);
        mfma_top2_kernel<<<dim3(KCODES / 128, NROWS / 128), 256, 0, stream>>>(A, B, esq, top2);
        reduce_top2_kernel<<<NROWS / 256, 256, 0, stream>>>(top2, bidx, flags);
        rescore_kernel<<<NROWS, 256, 0, stream>>>(x, emb, esq, flags, bidx);
    } else {
        argmin_fb_kernel<<<NROWS / BROWS, 256, 0, stream>>>(x, emb, esq, bidx);
    }

    gather_kernel<<<NROWS / 64, 256, 0, stream>>>(x, emb, bidx, out, partial);
    finalize_kernel<<<1, 256, 0, stream>>>(partial, out + 8388608);
}

// Round 6
// 1005.920 us; speedup vs baseline: 1.6082x; 1.4420x over previous
//
#include <hip/hip_runtime.h>

#define N_PIX 1024      // 32*32 pixels per image
#define BATCH 32
#define CCH 256         // channels == code dim
#define KCODES 4096
#define NROWS 32768     // BATCH * N_PIX
#define DELTA 0.0625f   // rescore margin (error bound ~0.005 worst case)

typedef __attribute__((ext_vector_type(8))) short bf16x8;
typedef __attribute__((ext_vector_type(4))) float f32x4;

// ---- ws layout (bytes) ----
#define OFF_ESQ   0u
#define OFF_BIDX  16384u
#define OFF_FLAGS 147456u
#define OFF_PART  278528u
#define OFF_TOP2  524288u                    // 64 chunks x 32768 rows x float4 = 32 MB
#define OFF_A     34078720u                  // 8 kt x 32768 x 128 B = 32 MB
#define OFF_B     67633152u                  // 8 kt x 4096 x 128 B = 4 MB
#define WS_NEEDED 71827456u

// round-to-nearest-even fp32 -> bf16 bits
__device__ __forceinline__ unsigned short f2bf(float v) {
    unsigned u = __float_as_uint(v);
    return (unsigned short)((u + 0x7FFFu + ((u >> 16) & 1u)) >> 16);
}
__device__ __forceinline__ float bf2f(unsigned short h) {
    return __uint_as_float(((unsigned)h) << 16);
}

__device__ __forceinline__ void gload_lds16(const void* g, void* l) {
    __builtin_amdgcn_global_load_lds(
        (const __attribute__((address_space(1))) unsigned int*)g,
        (__attribute__((address_space(3))) unsigned int*)l, 16, 0, 0);
}

// ---------------- kernel 0: e_sq[k] = sum_c emb[k][c]^2 (exact fp32) ----------------
__global__ __launch_bounds__(256) void esq_kernel(const float* __restrict__ emb,
                                                  float* __restrict__ esq) {
    const int t = threadIdx.x;
    const int w = t >> 6, l = t & 63;
    const int k = blockIdx.x * 4 + w;
    const float4 v = *(const float4*)(emb + (size_t)k * CCH + l * 4);
    float s = v.x * v.x + v.y * v.y + v.z * v.z + v.w * v.w;
#pragma unroll
    for (int off = 32; off > 0; off >>= 1) s += __shfl_down(s, off);
    if (l == 0) esq[k] = s;
}

// ---------------- conv_x: x fp32 NCHW -> pre-swizzled bf16 hi/lo tiles ----------------
// A[kt][m][128B]: kt 0-3 = hi(channels kt*64..+64), kt 4-7 = lo.
// within 128-row tile: byte(row, granule g) = (row*128 + g*16) ^ ((row&7)<<4)
__global__ __launch_bounds__(256) void conv_x_kernel(const float* __restrict__ x,
                                                     char* __restrict__ A) {
    const int t = threadIdx.x;
    const int m = blockIdx.x * 64 + (t & 63);
    const int kt = t >> 6;                       // 0..3
    const int b = m >> 10, p = m & 1023;
    const float* src = x + ((size_t)b * CCH + kt * 64) * N_PIX + p;
    char* hi_base = A + (size_t)kt * (NROWS * 128) + (size_t)(m >> 7) * 16384;
    char* lo_base = hi_base + (size_t)4 * (NROWS * 128);
    const int row = m & 127;
    const int swz = (row & 7) << 4;
#pragma unroll
    for (int g = 0; g < 8; ++g) {
        unsigned hv[4], lv[4];
#pragma unroll
        for (int e2 = 0; e2 < 4; ++e2) {
            const float v0 = src[(size_t)(g * 8 + e2 * 2 + 0) * N_PIX];
            const float v1 = src[(size_t)(g * 8 + e2 * 2 + 1) * N_PIX];
            const unsigned short h0 = f2bf(v0), h1 = f2bf(v1);
            const unsigned short l0 = f2bf(v0 - bf2f(h0)), l1 = f2bf(v1 - bf2f(h1));
            hv[e2] = (unsigned)h0 | ((unsigned)h1 << 16);
            lv[e2] = (unsigned)l0 | ((unsigned)l1 << 16);
        }
        const int byte = (row * 128 + g * 16) ^ swz;
        *(uint4*)(hi_base + byte) = make_uint4(hv[0], hv[1], hv[2], hv[3]);
        *(uint4*)(lo_base + byte) = make_uint4(lv[0], lv[1], lv[2], lv[3]);
    }
}

// ---------------- conv_e: embedding fp32 -> pre-swizzled bf16 hi/lo tiles ----------------
__global__ __launch_bounds__(256) void conv_e_kernel(const float* __restrict__ emb,
                                                     char* __restrict__ B) {
    const int t = threadIdx.x;
    const int n = blockIdx.x * 64 + (t & 63);
    const int kt = t >> 6;
    const float* src = emb + (size_t)n * CCH + kt * 64;
    char* hi_base = B + (size_t)kt * (KCODES * 128) + (size_t)(n >> 7) * 16384;
    char* lo_base = hi_base + (size_t)4 * (KCODES * 128);
    const int row = n & 127;
    const int swz = (row & 7) << 4;
#pragma unroll
    for (int g = 0; g < 8; ++g) {
        const float4 a = *(const float4*)(src + g * 8);
        const float4 c = *(const float4*)(src + g * 8 + 4);
        const float vr[8] = {a.x, a.y, a.z, a.w, c.x, c.y, c.z, c.w};
        unsigned hv[4], lv[4];
#pragma unroll
        for (int e2 = 0; e2 < 4; ++e2) {
            const unsigned short h0 = f2bf(vr[e2 * 2]), h1 = f2bf(vr[e2 * 2 + 1]);
            const unsigned short l0 = f2bf(vr[e2 * 2] - bf2f(h0));
            const unsigned short l1 = f2bf(vr[e2 * 2 + 1] - bf2f(h1));
            hv[e2] = (unsigned)h0 | ((unsigned)h1 << 16);
            lv[e2] = (unsigned)l0 | ((unsigned)l1 << 16);
        }
        const int byte = (row * 128 + g * 16) ^ swz;
        *(uint4*)(hi_base + byte) = make_uint4(hv[0], hv[1], hv[2], hv[3]);
        *(uint4*)(lo_base + byte) = make_uint4(lv[0], lv[1], lv[2], lv[3]);
    }
}

// ---------------- mfma_top2: 128x128 tile GEMM (12 K-subtiles of 64) + fused top-2 ----------------
// dot(m,n) = xh.eh + xl.eh + xh.el ; score = esq[n] - 2*dot
// 4 waves in 2x2; wave owns 64x64; 16x16x32 bf16 MFMA, 4x4 frags.
// m97 structure: single-buffer LDS, 2 barriers/K-step, global_load_lds w16,
// fully-unrolled K-walk (compile-time tile bases, no scratch), hoisted ds offsets.
__global__ __launch_bounds__(256, 3) void mfma_top2_kernel(
    const char* __restrict__ Ag, const char* __restrict__ Bg,
    const float* __restrict__ esq, float4* __restrict__ top2)
{
    __shared__ char lds[32768];   // A tile 16K | B tile 16K
    const int t = threadIdx.x;
    const int w = t >> 6, l = t & 63;
    const int mb = blockIdx.x;    // 0..255 row-block   (x-fastest: blocks share B-walk)
    const int nb = blockIdx.y;    // 0..31 code-block
    const int lh = l >> 4, ll = l & 15;

    // hoisted swizzled LDS fragment byte offsets (live in 16 regs across K-loop)
    int aoff[2][4], boff[2][4];
#pragma unroll
    for (int ks = 0; ks < 2; ++ks)
#pragma unroll
        for (int i = 0; i < 4; ++i) {
            const int ar = (w >> 1) * 64 + i * 16 + ll;
            aoff[ks][i] = (ar * 128 + ks * 64 + lh * 16) ^ ((ar & 7) << 4);
            const int br = (w & 1) * 64 + i * 16 + ll;
            boff[ks][i] = 16384 + ((br * 128 + ks * 64 + lh * 16) ^ ((br & 7) << 4));
        }

    const char* Abase = Ag + (size_t)mb * 16384;   // + PA * (NROWS*128) per subtile
    const char* Bbase = Bg + (size_t)nb * 16384;   // + PB * (KCODES*128)

    f32x4 acc[4][4];
#pragma unroll
    for (int i = 0; i < 4; ++i)
#pragma unroll
        for (int j = 0; j < 4; ++j) acc[i][j] = 0.f;

    // 12 products: (Ahi,Bhi) kt 0-3, (Alo,Bhi) kt 0-3, (Ahi,Blo) kt 0-3
    static constexpr int PA[12] = {0, 1, 2, 3, 4, 5, 6, 7, 0, 1, 2, 3};
    static constexpr int PB[12] = {0, 1, 2, 3, 0, 1, 2, 3, 4, 5, 6, 7};

#pragma unroll
    for (int pp = 0; pp < 12; ++pp) {
        const char* At = Abase + (size_t)PA[pp] * (NROWS * 128);
        const char* Bt = Bbase + (size_t)PB[pp] * (KCODES * 128);
        __syncthreads();                       // previous readers done before overwrite
#pragma unroll
        for (int i = 0; i < 4; ++i) {
            const int g16 = (i * 256 + t) * 16;
            gload_lds16(At + g16, lds + g16);
            gload_lds16(Bt + g16, lds + 16384 + g16);
        }
        __syncthreads();                       // compiler drains vmcnt(0) before s_barrier

#pragma unroll
        for (int ks = 0; ks < 2; ++ks) {
            bf16x8 af[4], bfr[4];
#pragma unroll
            for (int i = 0; i < 4; ++i) {
                af[i]  = *(const bf16x8*)(lds + aoff[ks][i]);
                bfr[i] = *(const bf16x8*)(lds + boff[ks][i]);
            }
#pragma unroll
            for (int i = 0; i < 4; ++i)
#pragma unroll
                for (int j = 0; j < 4; ++j)
                    acc[i][j] = __builtin_amdgcn_mfma_f32_16x16x32_bf16(af[i], bfr[j], acc[i][j], 0, 0, 0);
        }
    }

    // epilogue: per-row top2 over this wave's 64 cols.
    // C layout: col = ll, row = lh*4 + reg  (within each 16x16 tile)
    float b1[16], b2[16];
    int k1[16];
#pragma unroll
    for (int q = 0; q < 16; ++q) { b1[q] = 3.4e38f; b2[q] = 3.4e38f; k1[q] = 0; }
    const int colg0 = nb * 128 + (w & 1) * 64 + ll;
#pragma unroll
    for (int j = 0; j < 4; ++j) {
        const int kcol = colg0 + j * 16;
        const float eq = esq[kcol];
#pragma unroll
        for (int i = 0; i < 4; ++i)
#pragma unroll
            for (int r = 0; r < 4; ++r) {
                const float s = fmaf(-2.f, acc[i][j][r], eq);
                const int q = i * 4 + r;
                if (s < b1[q]) { b2[q] = b1[q]; b1[q] = s; k1[q] = kcol; }
                else if (s < b2[q]) { b2[q] = s; }
            }
    }
    // merge the 16 col-lanes (masks 1,2,4,8 stay within the 16-lane group)
#pragma unroll
    for (int msk = 1; msk <= 8; msk <<= 1) {
#pragma unroll
        for (int q = 0; q < 16; ++q) {
            const float ob1 = __shfl_xor(b1[q], msk, 64);
            const int   ok1 = __shfl_xor(k1[q], msk, 64);
            const float ob2 = __shfl_xor(b2[q], msk, 64);
            if (ob1 < b1[q] || (ob1 == b1[q] && ok1 < k1[q])) {
                b2[q] = fminf(b1[q], ob2); b1[q] = ob1; k1[q] = ok1;
            } else {
                b2[q] = fminf(b2[q], ob1);
            }
        }
    }
    if (ll == 0) {
        const size_t cc = (size_t)(nb * 2 + (w & 1)) * NROWS;
#pragma unroll
        for (int q = 0; q < 16; ++q) {
            const int i = q >> 2, r = q & 3;
            const int row = mb * 128 + (w >> 1) * 64 + i * 16 + lh * 4 + r;
            top2[cc + row] = make_float4(b1[q], __int_as_float(k1[q]), b2[q], 0.f);
        }
    }
}

// ---------------- reduce: merge 64 col-chunks per row; flag ambiguous rows ----------------
__global__ __launch_bounds__(256) void reduce_top2_kernel(const float4* __restrict__ top2,
                                                          int* __restrict__ bidx,
                                                          int* __restrict__ flags) {
    const int row = blockIdx.x * 256 + threadIdx.x;
    float b1 = 3.4e38f, b2 = 3.4e38f;
    int k1 = 0x7fffffff;
#pragma unroll 8
    for (int c = 0; c < 64; ++c) {
        const float4 v = top2[(size_t)c * NROWS + row];
        const float ob1 = v.x, ob2 = v.z;
        const int ok1 = __float_as_int(v.y);
        if (ob1 < b1 || (ob1 == b1 && ok1 < k1)) { b2 = fminf(b1, ob2); b1 = ob1; k1 = ok1; }
        else { b2 = fminf(b2, ob1); }
    }
    bidx[row] = k1;
    flags[row] = (b2 - b1 <= DELTA) ? 1 : 0;
}

// ---------------- rescore: exact fp32 argmin for flagged rows ----------------
__global__ __launch_bounds__(256) void rescore_kernel(const float* __restrict__ x,
                                                      const float* __restrict__ emb,
                                                      const float* __restrict__ esq,
                                                      const int* __restrict__ flags,
                                                      int* __restrict__ bidx) {
    const int row = blockIdx.x;
    if (!flags[row]) return;   // uniform across block
    __shared__ float xr[CCH];
    __shared__ float rs[256];
    __shared__ int rk[256];
    const int t = threadIdx.x;
    const int b = row >> 10, p = row & 1023;
    xr[t] = x[((size_t)b * CCH + t) * N_PIX + p];
    __syncthreads();
    float bs = 3.4e38f;
    int bi = 0x7fffffff;
    for (int k = t; k < KCODES; k += 256) {
        const float4* er = (const float4*)(emb + (size_t)k * CCH);
        float dot = 0.f;
#pragma unroll 16
        for (int c = 0; c < 64; ++c) {
            const float4 e4 = er[c];
            const float4 xv = *(const float4*)(xr + c * 4);
            dot = fmaf(xv.x, e4.x, dot);
            dot = fmaf(xv.y, e4.y, dot);
            dot = fmaf(xv.z, e4.z, dot);
            dot = fmaf(xv.w, e4.w, dot);
        }
        const float s = fmaf(-2.f, dot, esq[k]);
        if (s < bs || (s == bs && k < bi)) { bs = s; bi = k; }
    }
    rs[t] = bs; rk[t] = bi;
    __syncthreads();
    for (int s2 = 128; s2 > 0; s2 >>= 1) {
        if (t < s2) {
            if (rs[t + s2] < rs[t] || (rs[t + s2] == rs[t] && rk[t + s2] < rk[t])) {
                rs[t] = rs[t + s2]; rk[t] = rk[t + s2];
            }
        }
        __syncthreads();
    }
    if (t == 0) bidx[row] = rk[0];
}

// ---------------- fallback fp32 argmin (known-good) if ws too small ----------------
#define BROWS 32
#define FKTILE 256
#define FDCH 16
__global__ __launch_bounds__(256, 2) void argmin_fb_kernel(
    const float* __restrict__ x, const float* __restrict__ emb,
    const float* __restrict__ esq, int* __restrict__ bidx)
{
    __shared__ float xs[CCH * BROWS];
    __shared__ float es[FDCH * FKTILE];
    const int t = threadIdx.x;
    const int w = t >> 6;
    const int l = t & 63;
    const int n0 = blockIdx.x * BROWS;
    const int b = n0 >> 10;
    const int pixbase = n0 & (N_PIX - 1);
    const float* xb = x + (size_t)b * CCH * N_PIX + pixbase;
    {
        const int p4 = (t & 7) * 4;
        const int crow = t >> 3;
#pragma unroll
        for (int i = 0; i < 8; ++i) {
            const int c = i * 32 + crow;
            *(float4*)(xs + c * BROWS + p4) = *(const float4*)(xb + (size_t)c * N_PIX + p4);
        }
    }
    float best[8]; int bk[8];
#pragma unroll
    for (int r = 0; r < 8; ++r) { best[r] = 3.4e38f; bk[r] = 0; }
    float acc[8][4];
#pragma unroll
    for (int r = 0; r < 8; ++r)
#pragma unroll
        for (int j = 0; j < 4; ++j) acc[r][j] = 0.f;
    for (int kt = 0; kt < KCODES / FKTILE; ++kt) {
        for (int dc = 0; dc < CCH / FDCH; ++dc) {
            __syncthreads();
            {
                const float* src = emb + (size_t)(kt * FKTILE + t) * CCH + dc * FDCH;
#pragma unroll
                for (int c = 0; c < FDCH; ++c) es[c * FKTILE + t] = src[c];
            }
            __syncthreads();
            const int c0 = dc * FDCH;
            const float* ep = es + 4 * l;
            const float* xp = xs + c0 * BROWS + w * 8;
#pragma unroll
            for (int c = 0; c < FDCH; ++c) {
                const float4 ev = *(const float4*)(ep + c * FKTILE);
                const float4 xa = *(const float4*)(xp + c * BROWS);
                const float4 xc = *(const float4*)(xp + c * BROWS + 4);
                const float xr8[8] = {xa.x, xa.y, xa.z, xa.w, xc.x, xc.y, xc.z, xc.w};
#pragma unroll
                for (int r = 0; r < 8; ++r) {
                    acc[r][0] = fmaf(xr8[r], ev.x, acc[r][0]);
                    acc[r][1] = fmaf(xr8[r], ev.y, acc[r][1]);
                    acc[r][2] = fmaf(xr8[r], ev.z, acc[r][2]);
                    acc[r][3] = fmaf(xr8[r], ev.w, acc[r][3]);
                }
            }
        }
        const float4 q = *(const float4*)(esq + kt * FKTILE + 4 * l);
        const float qr[4] = {q.x, q.y, q.z, q.w};
#pragma unroll
        for (int r = 0; r < 8; ++r)
#pragma unroll
            for (int j = 0; j < 4; ++j) {
                const float s = fmaf(-2.f, acc[r][j], qr[j]);
                if (s < best[r]) { best[r] = s; bk[r] = kt * FKTILE + 4 * l + j; }
                acc[r][j] = 0.f;
            }
    }
#pragma unroll
    for (int r = 0; r < 8; ++r) {
        float bv = best[r]; int bi = bk[r];
#pragma unroll
        for (int off = 32; off > 0; off >>= 1) {
            const float ov = __shfl_xor(bv, off, 64);
            const int   oi = __shfl_xor(bi, off, 64);
            if (ov < bv || (ov == bv && oi < bi)) { bv = ov; bi = oi; }
        }
        if (l == 0) bidx[n0 + w * 8 + r] = bi;
    }
}

// ---------------- gather + oup + loss partials ----------------
__global__ __launch_bounds__(256) void gather_kernel(
    const float* __restrict__ x, const float* __restrict__ emb,
    const int* __restrict__ bidx, float* __restrict__ oup,
    float* __restrict__ partial)
{
    __shared__ int sidx[64];
    __shared__ float red[256];
    const int t = threadIdx.x;
    const int n0 = blockIdx.x * 64;
    const int b = n0 >> 10;
    const int pixbase = n0 & (N_PIX - 1);
    if (t < 64) sidx[t] = bidx[n0 + t];
    __syncthreads();
    const int pl = t & 63;
    const int w = t >> 6;
    const int k = sidx[pl];
    const float* xbp = x + (size_t)b * CCH * N_PIX + pixbase + pl;
    float* ob = oup + (size_t)b * CCH * N_PIX + pixbase + pl;
    const float* ek = emb + (size_t)k * CCH + w * 64;
    float lsum = 0.f;
#pragma unroll 4
    for (int cc = 0; cc < 16; ++cc) {
        const float4 e4 = *(const float4*)(ek + cc * 4);
        const float er[4] = {e4.x, e4.y, e4.z, e4.w};
#pragma unroll
        for (int j = 0; j < 4; ++j) {
            const size_t off = (size_t)(w * 64 + cc * 4 + j) * N_PIX;
            const float xv = xbp[off];
            ob[off] = er[j];
            const float d = xv - er[j];
            lsum = fmaf(d, d, lsum);
        }
    }
    red[t] = lsum;
    __syncthreads();
#pragma unroll
    for (int s = 128; s > 0; s >>= 1) {
        if (t < s) red[t] += red[t + s];
        __syncthreads();
    }
    if (t == 0) partial[blockIdx.x] = red[0];
}

__global__ __launch_bounds__(256) void finalize_kernel(const float* __restrict__ partial,
                                                       float* __restrict__ out_losses) {
    __shared__ float red[256];
    const int t = threadIdx.x;
    red[t] = partial[t] + partial[t + 256];
    __syncthreads();
    for (int s = 128; s > 0; s >>= 1) {
        if (t < s) red[t] += red[t + s];
        __syncthreads();
    }
    if (t == 0) {
        const float loss = red[0] * (1.0f / 8388608.0f);
        out_losses[0] = loss;
        out_losses[1] = loss;
    }
}

extern "C" void kernel_launch(void* const* d_in, const int* in_sizes, int n_in,
                              void* d_out, int out_size, void* d_ws, size_t ws_size,
                              hipStream_t stream) {
    const float* x = (const float*)d_in[0];
    const float* emb = (const float*)d_in[1];
    float* out = (float*)d_out;

    char* ws = (char*)d_ws;
    float* esq = (float*)(ws + OFF_ESQ);
    int* bidx = (int*)(ws + OFF_BIDX);
    int* flags = (int*)(ws + OFF_FLAGS);
    float* partial = (float*)(ws + OFF_PART);

    esq_kernel<<<KCODES / 4, 256, 0, stream>>>(emb, esq);

    if (ws_size >= (size_t)WS_NEEDED) {
        float4* top2 = (float4*)(ws + OFF_TOP2);
        char* A = ws + OFF_A;
        char* B = ws + OFF_B;
        conv_x_kernel<<<NROWS / 64, 256, 0, stream>>>(x, A);
        conv_e_kernel<<<KCODES / 64, 256, 0, stream>>>(emb, B);
        mfma_top2_kernel<<<dim3(NROWS / 128, KCODES / 128), 256, 0, stream>>>(A, B, esq, top2);
        reduce_top2_kernel<<<NROWS / 256, 256, 0, stream>>>(top2, bidx, flags);
        rescore_kernel<<<NROWS, 256, 0, stream>>>(x, emb, esq, flags, bidx);
    } else {
        argmin_fb_kernel<<<NROWS / BROWS, 256, 0, stream>>>(x, emb, esq, bidx);
    }

    gather_kernel<<<NROWS / 64, 256, 0, stream>>>(x, emb, bidx, out, partial);
    finalize_kernel<<<1, 256, 0, stream>>>(partial, out + 8388608);
}

// Round 7
// 579.761 us; speedup vs baseline: 2.7903x; 1.7351x over previous
//
#include <hip/hip_runtime.h>

#define N_PIX 1024      // 32*32 pixels per image
#define BATCH 32
#define CCH 256         // channels == code dim
#define KCODES 4096
#define NROWS 32768     // BATCH * N_PIX
#define DELTA 0.0625f   // rescore margin (approx-score error bound ~0.003 typ, 0.05 worst)

typedef __attribute__((ext_vector_type(8))) short bf16x8;
typedef __attribute__((ext_vector_type(4))) float f32x4;

// ---- ws layout (bytes) ----
#define OFF_ESQ   0u
#define OFF_BIDX  16384u
#define OFF_FLAGS 147456u
#define OFF_PART  278528u
#define OFF_TOP2  524288u                    // 64 chunks x 32768 rows x float4 = 32 MB
#define OFF_A     34078720u                  // 8 kt x 32768 x 128 B = 32 MB
#define OFF_B     67633152u                  // 8 kt x 4096 x 128 B = 4 MB
#define WS_NEEDED 71827456u
// list/res/cnt live INSIDE the A region (dead after mfma_top2; rewritten每 call by conv_x first)
#define OFF_LIST  OFF_A                      // 32768 i32 = 128 KB
#define OFF_RES   (OFF_A + 131072u)          // 32768 u64 = 256 KB
#define OFF_CNT   (OFF_A + 131072u + 262144u)

// round-to-nearest-even fp32 -> bf16 bits
__device__ __forceinline__ unsigned short f2bf(float v) {
    unsigned u = __float_as_uint(v);
    return (unsigned short)((u + 0x7FFFu + ((u >> 16) & 1u)) >> 16);
}
__device__ __forceinline__ float bf2f(unsigned short h) {
    return __uint_as_float(((unsigned)h) << 16);
}
// monotone float -> uint (total order preserving)
__device__ __forceinline__ unsigned mono(float s) {
    unsigned u = __float_as_uint(s);
    return (u & 0x80000000u) ? ~u : (u | 0x80000000u);
}

__device__ __forceinline__ void gload_lds16(const void* g, void* l) {
    __builtin_amdgcn_global_load_lds(
        (const __attribute__((address_space(1))) unsigned int*)g,
        (__attribute__((address_space(3))) unsigned int*)l, 16, 0, 0);
}

// ---------------- kernel 0: e_sq[k] = sum_c emb[k][c]^2 (exact fp32) ----------------
__global__ __launch_bounds__(256) void esq_kernel(const float* __restrict__ emb,
                                                  float* __restrict__ esq) {
    const int t = threadIdx.x;
    const int w = t >> 6, l = t & 63;
    const int k = blockIdx.x * 4 + w;
    const float4 v = *(const float4*)(emb + (size_t)k * CCH + l * 4);
    float s = v.x * v.x + v.y * v.y + v.z * v.z + v.w * v.w;
#pragma unroll
    for (int off = 32; off > 0; off >>= 1) s += __shfl_down(s, off);
    if (l == 0) esq[k] = s;
}

// ---------------- conv_x: x fp32 NCHW -> pre-swizzled bf16 hi/lo tiles ----------------
__global__ __launch_bounds__(256) void conv_x_kernel(const float* __restrict__ x,
                                                     char* __restrict__ A) {
    const int t = threadIdx.x;
    const int m = blockIdx.x * 64 + (t & 63);
    const int kt = t >> 6;                       // 0..3
    const int b = m >> 10, p = m & 1023;
    const float* src = x + ((size_t)b * CCH + kt * 64) * N_PIX + p;
    char* hi_base = A + (size_t)kt * (NROWS * 128) + (size_t)(m >> 7) * 16384;
    char* lo_base = hi_base + (size_t)4 * (NROWS * 128);
    const int row = m & 127;
    const int swz = (row & 7) << 4;
#pragma unroll
    for (int g = 0; g < 8; ++g) {
        unsigned hv[4], lv[4];
#pragma unroll
        for (int e2 = 0; e2 < 4; ++e2) {
            const float v0 = src[(size_t)(g * 8 + e2 * 2 + 0) * N_PIX];
            const float v1 = src[(size_t)(g * 8 + e2 * 2 + 1) * N_PIX];
            const unsigned short h0 = f2bf(v0), h1 = f2bf(v1);
            const unsigned short l0 = f2bf(v0 - bf2f(h0)), l1 = f2bf(v1 - bf2f(h1));
            hv[e2] = (unsigned)h0 | ((unsigned)h1 << 16);
            lv[e2] = (unsigned)l0 | ((unsigned)l1 << 16);
        }
        const int byte = (row * 128 + g * 16) ^ swz;
        *(uint4*)(hi_base + byte) = make_uint4(hv[0], hv[1], hv[2], hv[3]);
        *(uint4*)(lo_base + byte) = make_uint4(lv[0], lv[1], lv[2], lv[3]);
    }
}

// ---------------- conv_e: embedding fp32 -> pre-swizzled bf16 hi/lo tiles (+zero cnt) ----------------
__global__ __launch_bounds__(256) void conv_e_kernel(const float* __restrict__ emb,
                                                     char* __restrict__ B,
                                                     int* __restrict__ cnt) {
    const int t = threadIdx.x;
    if (blockIdx.x == 0 && t == 0) *cnt = 0;   // runs after conv_x (which clobbers this region)
    const int n = blockIdx.x * 64 + (t & 63);
    const int kt = t >> 6;
    const float* src = emb + (size_t)n * CCH + kt * 64;
    char* hi_base = B + (size_t)kt * (KCODES * 128) + (size_t)(n >> 7) * 16384;
    char* lo_base = hi_base + (size_t)4 * (KCODES * 128);
    const int row = n & 127;
    const int swz = (row & 7) << 4;
#pragma unroll
    for (int g = 0; g < 8; ++g) {
        const float4 a = *(const float4*)(src + g * 8);
        const float4 c = *(const float4*)(src + g * 8 + 4);
        const float vr[8] = {a.x, a.y, a.z, a.w, c.x, c.y, c.z, c.w};
        unsigned hv[4], lv[4];
#pragma unroll
        for (int e2 = 0; e2 < 4; ++e2) {
            const unsigned short h0 = f2bf(vr[e2 * 2]), h1 = f2bf(vr[e2 * 2 + 1]);
            const unsigned short l0 = f2bf(vr[e2 * 2] - bf2f(h0));
            const unsigned short l1 = f2bf(vr[e2 * 2 + 1] - bf2f(h1));
            hv[e2] = (unsigned)h0 | ((unsigned)h1 << 16);
            lv[e2] = (unsigned)l0 | ((unsigned)l1 << 16);
        }
        const int byte = (row * 128 + g * 16) ^ swz;
        *(uint4*)(hi_base + byte) = make_uint4(hv[0], hv[1], hv[2], hv[3]);
        *(uint4*)(lo_base + byte) = make_uint4(lv[0], lv[1], lv[2], lv[3]);
    }
}

// ---------------- mfma_top2: 128x128 tile GEMM (12 K-subtiles of 64) + fused top-2 ----------------
__global__ __launch_bounds__(256, 3) void mfma_top2_kernel(
    const char* __restrict__ Ag, const char* __restrict__ Bg,
    const float* __restrict__ esq, float4* __restrict__ top2)
{
    __shared__ char lds[32768];   // A tile 16K | B tile 16K
    const int t = threadIdx.x;
    const int w = t >> 6, l = t & 63;
    const int mb = blockIdx.x;    // row-block (x-fastest: blocks share B-walk)
    const int nb = blockIdx.y;    // code-block
    const int lh = l >> 4, ll = l & 15;

    int aoff[2][4], boff[2][4];
#pragma unroll
    for (int ks = 0; ks < 2; ++ks)
#pragma unroll
        for (int i = 0; i < 4; ++i) {
            const int ar = (w >> 1) * 64 + i * 16 + ll;
            aoff[ks][i] = (ar * 128 + ks * 64 + lh * 16) ^ ((ar & 7) << 4);
            const int br = (w & 1) * 64 + i * 16 + ll;
            boff[ks][i] = 16384 + ((br * 128 + ks * 64 + lh * 16) ^ ((br & 7) << 4));
        }

    const char* Abase = Ag + (size_t)mb * 16384;
    const char* Bbase = Bg + (size_t)nb * 16384;

    f32x4 acc[4][4];
#pragma unroll
    for (int i = 0; i < 4; ++i)
#pragma unroll
        for (int j = 0; j < 4; ++j) acc[i][j] = 0.f;

    static constexpr int PA[12] = {0, 1, 2, 3, 4, 5, 6, 7, 0, 1, 2, 3};
    static constexpr int PB[12] = {0, 1, 2, 3, 0, 1, 2, 3, 4, 5, 6, 7};

#pragma unroll
    for (int pp = 0; pp < 12; ++pp) {
        const char* At = Abase + (size_t)PA[pp] * (NROWS * 128);
        const char* Bt = Bbase + (size_t)PB[pp] * (KCODES * 128);
        __syncthreads();
#pragma unroll
        for (int i = 0; i < 4; ++i) {
            const int g16 = (i * 256 + t) * 16;
            gload_lds16(At + g16, lds + g16);
            gload_lds16(Bt + g16, lds + 16384 + g16);
        }
        __syncthreads();

#pragma unroll
        for (int ks = 0; ks < 2; ++ks) {
            bf16x8 af[4], bfr[4];
#pragma unroll
            for (int i = 0; i < 4; ++i) {
                af[i]  = *(const bf16x8*)(lds + aoff[ks][i]);
                bfr[i] = *(const bf16x8*)(lds + boff[ks][i]);
            }
#pragma unroll
            for (int i = 0; i < 4; ++i)
#pragma unroll
                for (int j = 0; j < 4; ++j)
                    acc[i][j] = __builtin_amdgcn_mfma_f32_16x16x32_bf16(af[i], bfr[j], acc[i][j], 0, 0, 0);
        }
    }

    // epilogue: per-row top2 over this wave's 64 cols.
    float b1[16], b2[16];
    int k1[16];
#pragma unroll
    for (int q = 0; q < 16; ++q) { b1[q] = 3.4e38f; b2[q] = 3.4e38f; k1[q] = 0; }
    const int colg0 = nb * 128 + (w & 1) * 64 + ll;
#pragma unroll
    for (int j = 0; j < 4; ++j) {
        const int kcol = colg0 + j * 16;
        const float eq = esq[kcol];
#pragma unroll
        for (int i = 0; i < 4; ++i)
#pragma unroll
            for (int r = 0; r < 4; ++r) {
                const float s = fmaf(-2.f, acc[i][j][r], eq);
                const int q = i * 4 + r;
                if (s < b1[q]) { b2[q] = b1[q]; b1[q] = s; k1[q] = kcol; }
                else if (s < b2[q]) { b2[q] = s; }
            }
    }
#pragma unroll
    for (int msk = 1; msk <= 8; msk <<= 1) {
#pragma unroll
        for (int q = 0; q < 16; ++q) {
            const float ob1 = __shfl_xor(b1[q], msk, 64);
            const int   ok1 = __shfl_xor(k1[q], msk, 64);
            const float ob2 = __shfl_xor(b2[q], msk, 64);
            if (ob1 < b1[q] || (ob1 == b1[q] && ok1 < k1[q])) {
                b2[q] = fminf(b1[q], ob2); b1[q] = ob1; k1[q] = ok1;
            } else {
                b2[q] = fminf(b2[q], ob1);
            }
        }
    }
    if (ll == 0) {
        const size_t cc = (size_t)(nb * 2 + (w & 1)) * NROWS;
#pragma unroll
        for (int q = 0; q < 16; ++q) {
            const int i = q >> 2, r = q & 3;
            const int row = mb * 128 + (w >> 1) * 64 + i * 16 + lh * 4 + r;
            top2[cc + row] = make_float4(b1[q], __int_as_float(k1[q]), b2[q], 0.f);
        }
    }
}

// ---------------- reduce: merge 64 col-chunks per row; compact ambiguous rows ----------------
__global__ __launch_bounds__(256) void reduce_top2_kernel(const float4* __restrict__ top2,
                                                          int* __restrict__ bidx,
                                                          int* __restrict__ flags,
                                                          int* __restrict__ list,
                                                          unsigned long long* __restrict__ res,
                                                          int* __restrict__ cnt) {
    const int row = blockIdx.x * 256 + threadIdx.x;
    float b1 = 3.4e38f, b2 = 3.4e38f;
    int k1 = 0x7fffffff;
#pragma unroll 8
    for (int c = 0; c < 64; ++c) {
        const float4 v = top2[(size_t)c * NROWS + row];
        const float ob1 = v.x, ob2 = v.z;
        const int ok1 = __float_as_int(v.y);
        if (ob1 < b1 || (ob1 == b1 && ok1 < k1)) { b2 = fminf(b1, ob2); b1 = ob1; k1 = ok1; }
        else { b2 = fminf(b2, ob1); }
    }
    bidx[row] = k1;
    const int f = (b2 - b1 <= DELTA) ? 1 : 0;
    flags[row] = f;
    if (f) {
        res[row] = ~0ULL;
        const int slot = atomicAdd(cnt, 1);
        list[slot] = row;
    }
}

// ---------------- rescore8: exact fp32 rescore, 8 rows x 256-code chunk per block ----------------
// grid = 2048 blocks: (blockIdx>>4) = entry-group (stride 128 groups), (blockIdx&15) = code chunk.
__global__ __launch_bounds__(256) void rescore8_kernel(const float* __restrict__ x,
                                                       const float* __restrict__ emb,
                                                       const float* __restrict__ esq,
                                                       const int* __restrict__ list,
                                                       const int* __restrict__ cnt,
                                                       unsigned long long* __restrict__ res) {
    __shared__ float xs[8][CCH];
    __shared__ int rid[8];
    const int t = threadIdx.x;
    const int q = blockIdx.x & 15;            // code chunk
    const int eg = blockIdx.x >> 4;           // entry group
    const int count = *cnt;
    const int k = q * 256 + t;
    const float eq = esq[k];
    const float* ek = emb + (size_t)k * CCH;

    for (int e8 = eg * 8; e8 < count; e8 += 128 * 8) {
        // stage row ids + 8 x-rows
        if (t < 8) rid[t] = (e8 + t < count) ? list[e8 + t] : -1;
        __syncthreads();
#pragma unroll
        for (int r = 0; r < 8; ++r) {
            const int rr = rid[r];
            if (rr >= 0) {
                const int b = rr >> 10, p = rr & 1023;
                xs[r][t] = x[((size_t)b * CCH + t) * N_PIX + p];
            }
        }
        __syncthreads();

        float dot[8];
#pragma unroll
        for (int r = 0; r < 8; ++r) dot[r] = 0.f;
#pragma unroll 8
        for (int c4 = 0; c4 < 64; ++c4) {
            const float4 e4 = *(const float4*)(ek + c4 * 4);
#pragma unroll
            for (int r = 0; r < 8; ++r) {
                const float4 xv = *(const float4*)(&xs[r][c4 * 4]);
                dot[r] = fmaf(xv.x, e4.x, dot[r]);
                dot[r] = fmaf(xv.y, e4.y, dot[r]);
                dot[r] = fmaf(xv.z, e4.z, dot[r]);
                dot[r] = fmaf(xv.w, e4.w, dot[r]);
            }
        }
        // per-row wave-min then one atomic per wave per row
#pragma unroll
        for (int r = 0; r < 8; ++r) {
            const float s = fmaf(-2.f, dot[r], eq);
            unsigned long long key = (((unsigned long long)mono(s)) << 32) | (unsigned)k;
#pragma unroll
            for (int off = 32; off > 0; off >>= 1) {
                const unsigned long long ok = __shfl_xor(key, off, 64);
                if (ok < key) key = ok;
            }
            if ((t & 63) == 0 && rid[r] >= 0)
                atomicMin(&res[rid[r]], key);
        }
        __syncthreads();
    }
}

// ---------------- apply: copy resolved indices for flagged rows ----------------
__global__ __launch_bounds__(256) void apply_kernel(const int* __restrict__ flags,
                                                    const unsigned long long* __restrict__ res,
                                                    int* __restrict__ bidx) {
    const int row = blockIdx.x * 256 + threadIdx.x;
    if (flags[row]) bidx[row] = (int)(res[row] & 0xFFFFFFFFULL);
}

// ---------------- fallback fp32 argmin (known-good) if ws too small ----------------
#define BROWS 32
#define FKTILE 256
#define FDCH 16
__global__ __launch_bounds__(256, 2) void argmin_fb_kernel(
    const float* __restrict__ x, const float* __restrict__ emb,
    const float* __restrict__ esq, int* __restrict__ bidx)
{
    __shared__ float xs[CCH * BROWS];
    __shared__ float es[FDCH * FKTILE];
    const int t = threadIdx.x;
    const int w = t >> 6;
    const int l = t & 63;
    const int n0 = blockIdx.x * BROWS;
    const int b = n0 >> 10;
    const int pixbase = n0 & (N_PIX - 1);
    const float* xb = x + (size_t)b * CCH * N_PIX + pixbase;
    {
        const int p4 = (t & 7) * 4;
        const int crow = t >> 3;
#pragma unroll
        for (int i = 0; i < 8; ++i) {
            const int c = i * 32 + crow;
            *(float4*)(xs + c * BROWS + p4) = *(const float4*)(xb + (size_t)c * N_PIX + p4);
        }
    }
    float best[8]; int bk[8];
#pragma unroll
    for (int r = 0; r < 8; ++r) { best[r] = 3.4e38f; bk[r] = 0; }
    float acc[8][4];
#pragma unroll
    for (int r = 0; r < 8; ++r)
#pragma unroll
        for (int j = 0; j < 4; ++j) acc[r][j] = 0.f;
    for (int kt = 0; kt < KCODES / FKTILE; ++kt) {
        for (int dc = 0; dc < CCH / FDCH; ++dc) {
            __syncthreads();
            {
                const float* src = emb + (size_t)(kt * FKTILE + t) * CCH + dc * FDCH;
#pragma unroll
                for (int c = 0; c < FDCH; ++c) es[c * FKTILE + t] = src[c];
            }
            __syncthreads();
            const int c0 = dc * FDCH;
            const float* ep = es + 4 * l;
            const float* xp = xs + c0 * BROWS + w * 8;
#pragma unroll
            for (int c = 0; c < FDCH; ++c) {
                const float4 ev = *(const float4*)(ep + c * FKTILE);
                const float4 xa = *(const float4*)(xp + c * BROWS);
                const float4 xc = *(const float4*)(xp + c * BROWS + 4);
                const float xr8[8] = {xa.x, xa.y, xa.z, xa.w, xc.x, xc.y, xc.z, xc.w};
#pragma unroll
                for (int r = 0; r < 8; ++r) {
                    acc[r][0] = fmaf(xr8[r], ev.x, acc[r][0]);
                    acc[r][1] = fmaf(xr8[r], ev.y, acc[r][1]);
                    acc[r][2] = fmaf(xr8[r], ev.z, acc[r][2]);
                    acc[r][3] = fmaf(xr8[r], ev.w, acc[r][3]);
                }
            }
        }
        const float4 q = *(const float4*)(esq + kt * FKTILE + 4 * l);
        const float qr[4] = {q.x, q.y, q.z, q.w};
#pragma unroll
        for (int r = 0; r < 8; ++r)
#pragma unroll
            for (int j = 0; j < 4; ++j) {
                const float s = fmaf(-2.f, acc[r][j], qr[j]);
                if (s < best[r]) { best[r] = s; bk[r] = kt * FKTILE + 4 * l + j; }
                acc[r][j] = 0.f;
            }
    }
#pragma unroll
    for (int r = 0; r < 8; ++r) {
        float bv = best[r]; int bi = bk[r];
#pragma unroll
        for (int off = 32; off > 0; off >>= 1) {
            const float ov = __shfl_xor(bv, off, 64);
            const int   oi = __shfl_xor(bi, off, 64);
            if (ov < bv || (ov == bv && oi < bi)) { bv = ov; bi = oi; }
        }
        if (l == 0) bidx[n0 + w * 8 + r] = bi;
    }
}

// ---------------- gather + oup + loss partials ----------------
__global__ __launch_bounds__(256) void gather_kernel(
    const float* __restrict__ x, const float* __restrict__ emb,
    const int* __restrict__ bidx, float* __restrict__ oup,
    float* __restrict__ partial)
{
    __shared__ int sidx[64];
    __shared__ float red[256];
    const int t = threadIdx.x;
    const int n0 = blockIdx.x * 64;
    const int b = n0 >> 10;
    const int pixbase = n0 & (N_PIX - 1);
    if (t < 64) sidx[t] = bidx[n0 + t];
    __syncthreads();
    const int pl = t & 63;
    const int w = t >> 6;
    const int k = sidx[pl];
    const float* xbp = x + (size_t)b * CCH * N_PIX + pixbase + pl;
    float* ob = oup + (size_t)b * CCH * N_PIX + pixbase + pl;
    const float* ek = emb + (size_t)k * CCH + w * 64;
    float lsum = 0.f;
#pragma unroll 4
    for (int cc = 0; cc < 16; ++cc) {
        const float4 e4 = *(const float4*)(ek + cc * 4);
        const float er[4] = {e4.x, e4.y, e4.z, e4.w};
#pragma unroll
        for (int j = 0; j < 4; ++j) {
            const size_t off = (size_t)(w * 64 + cc * 4 + j) * N_PIX;
            const float xv = xbp[off];
            ob[off] = er[j];
            const float d = xv - er[j];
            lsum = fmaf(d, d, lsum);
        }
    }
    red[t] = lsum;
    __syncthreads();
#pragma unroll
    for (int s = 128; s > 0; s >>= 1) {
        if (t < s) red[t] += red[t + s];
        __syncthreads();
    }
    if (t == 0) partial[blockIdx.x] = red[0];
}

__global__ __launch_bounds__(256) void finalize_kernel(const float* __restrict__ partial,
                                                       float* __restrict__ out_losses) {
    __shared__ float red[256];
    const int t = threadIdx.x;
    red[t] = partial[t] + partial[t + 256];
    __syncthreads();
    for (int s = 128; s > 0; s >>= 1) {
        if (t < s) red[t] += red[t + s];
        __syncthreads();
    }
    if (t == 0) {
        const float loss = red[0] * (1.0f / 8388608.0f);
        out_losses[0] = loss;
        out_losses[1] = loss;
    }
}

extern "C" void kernel_launch(void* const* d_in, const int* in_sizes, int n_in,
                              void* d_out, int out_size, void* d_ws, size_t ws_size,
                              hipStream_t stream) {
    const float* x = (const float*)d_in[0];
    const float* emb = (const float*)d_in[1];
    float* out = (float*)d_out;

    char* ws = (char*)d_ws;
    float* esq = (float*)(ws + OFF_ESQ);
    int* bidx = (int*)(ws + OFF_BIDX);
    int* flags = (int*)(ws + OFF_FLAGS);
    float* partial = (float*)(ws + OFF_PART);

    esq_kernel<<<KCODES / 4, 256, 0, stream>>>(emb, esq);

    if (ws_size >= (size_t)WS_NEEDED) {
        float4* top2 = (float4*)(ws + OFF_TOP2);
        char* A = ws + OFF_A;
        char* B = ws + OFF_B;
        int* list = (int*)(ws + OFF_LIST);
        unsigned long long* res = (unsigned long long*)(ws + OFF_RES);
        int* cnt = (int*)(ws + OFF_CNT);
        conv_x_kernel<<<NROWS / 64, 256, 0, stream>>>(x, A);
        conv_e_kernel<<<KCODES / 64, 256, 0, stream>>>(emb, B, cnt);
        mfma_top2_kernel<<<dim3(NROWS / 128, KCODES / 128), 256, 0, stream>>>(A, B, esq, top2);
        reduce_top2_kernel<<<NROWS / 256, 256, 0, stream>>>(top2, bidx, flags, list, res, cnt);
        rescore8_kernel<<<2048, 256, 0, stream>>>(x, emb, esq, list, cnt, res);
        apply_kernel<<<NROWS / 256, 256, 0, stream>>>(flags, res, bidx);
    } else {
        argmin_fb_kernel<<<NROWS / BROWS, 256, 0, stream>>>(x, emb, esq, bidx);
    }

    gather_kernel<<<NROWS / 64, 256, 0, stream>>>(x, emb, bidx, out, partial);
    finalize_kernel<<<1, 256, 0, stream>>>(partial, out + 8388608);
}

// Round 8
// 574.508 us; speedup vs baseline: 2.8158x; 1.0091x over previous
//
#include <hip/hip_runtime.h>

#define N_PIX 1024      // 32*32 pixels per image
#define BATCH 32
#define CCH 256         // channels == code dim
#define KCODES 4096
#define NROWS 32768     // BATCH * N_PIX
#define DELTA 0.0625f   // rescore margin (approx-score error bound ~0.003 typ, 0.05 worst)

typedef __attribute__((ext_vector_type(8))) short bf16x8;
typedef __attribute__((ext_vector_type(4))) float f32x4;

// ---- ws layout (bytes) ----
#define OFF_ESQ   0u
#define OFF_BIDX  16384u
#define OFF_FLAGS 147456u
#define OFF_PART  278528u
#define OFF_TOP2  524288u                    // 64 chunks x 32768 rows x float4 = 32 MB
#define OFF_A     34078720u                  // 8 kt x 32768 x 128 B = 32 MB
#define OFF_B     67633152u                  // 8 kt x 4096 x 128 B = 4 MB
#define WS_NEEDED 71827456u
// list/res/cnt live INSIDE the A region (dead after mfma_top2; rewritten every call by conv_x first)
#define OFF_LIST  OFF_A                      // 32768 i32 = 128 KB
#define OFF_RES   (OFF_A + 131072u)          // 32768 u64 = 256 KB
#define OFF_CNT   (OFF_A + 131072u + 262144u)

// round-to-nearest-even fp32 -> bf16 bits
__device__ __forceinline__ unsigned short f2bf(float v) {
    unsigned u = __float_as_uint(v);
    return (unsigned short)((u + 0x7FFFu + ((u >> 16) & 1u)) >> 16);
}
__device__ __forceinline__ float bf2f(unsigned short h) {
    return __uint_as_float(((unsigned)h) << 16);
}
// monotone float -> uint (total order preserving)
__device__ __forceinline__ unsigned mono(float s) {
    unsigned u = __float_as_uint(s);
    return (u & 0x80000000u) ? ~u : (u | 0x80000000u);
}

__device__ __forceinline__ void gload_lds16(const void* g, void* l) {
    __builtin_amdgcn_global_load_lds(
        (const __attribute__((address_space(1))) unsigned int*)g,
        (__attribute__((address_space(3))) unsigned int*)l, 16, 0, 0);
}

// ---------------- kernel 0: e_sq[k] = sum_c emb[k][c]^2 (exact fp32) ----------------
__global__ __launch_bounds__(256) void esq_kernel(const float* __restrict__ emb,
                                                  float* __restrict__ esq) {
    const int t = threadIdx.x;
    const int w = t >> 6, l = t & 63;
    const int k = blockIdx.x * 4 + w;
    const float4 v = *(const float4*)(emb + (size_t)k * CCH + l * 4);
    float s = v.x * v.x + v.y * v.y + v.z * v.z + v.w * v.w;
#pragma unroll
    for (int off = 32; off > 0; off >>= 1) s += __shfl_down(s, off);
    if (l == 0) esq[k] = s;
}

// ---------------- conv_x: x fp32 NCHW -> pre-swizzled bf16 hi/lo tiles ----------------
__global__ __launch_bounds__(256) void conv_x_kernel(const float* __restrict__ x,
                                                     char* __restrict__ A) {
    const int t = threadIdx.x;
    const int m = blockIdx.x * 64 + (t & 63);
    const int kt = t >> 6;                       // 0..3
    const int b = m >> 10, p = m & 1023;
    const float* src = x + ((size_t)b * CCH + kt * 64) * N_PIX + p;
    char* hi_base = A + (size_t)kt * (NROWS * 128) + (size_t)(m >> 7) * 16384;
    char* lo_base = hi_base + (size_t)4 * (NROWS * 128);
    const int row = m & 127;
    const int swz = (row & 7) << 4;
#pragma unroll
    for (int g = 0; g < 8; ++g) {
        unsigned hv[4], lv[4];
#pragma unroll
        for (int e2 = 0; e2 < 4; ++e2) {
            const float v0 = src[(size_t)(g * 8 + e2 * 2 + 0) * N_PIX];
            const float v1 = src[(size_t)(g * 8 + e2 * 2 + 1) * N_PIX];
            const unsigned short h0 = f2bf(v0), h1 = f2bf(v1);
            const unsigned short l0 = f2bf(v0 - bf2f(h0)), l1 = f2bf(v1 - bf2f(h1));
            hv[e2] = (unsigned)h0 | ((unsigned)h1 << 16);
            lv[e2] = (unsigned)l0 | ((unsigned)l1 << 16);
        }
        const int byte = (row * 128 + g * 16) ^ swz;
        *(uint4*)(hi_base + byte) = make_uint4(hv[0], hv[1], hv[2], hv[3]);
        *(uint4*)(lo_base + byte) = make_uint4(lv[0], lv[1], lv[2], lv[3]);
    }
}

// ---------------- conv_e: embedding fp32 -> pre-swizzled bf16 hi/lo tiles (+zero cnt) ----------------
__global__ __launch_bounds__(256) void conv_e_kernel(const float* __restrict__ emb,
                                                     char* __restrict__ B,
                                                     int* __restrict__ cnt) {
    const int t = threadIdx.x;
    if (blockIdx.x == 0 && t == 0) *cnt = 0;   // runs after conv_x (which clobbers this region)
    const int n = blockIdx.x * 64 + (t & 63);
    const int kt = t >> 6;
    const float* src = emb + (size_t)n * CCH + kt * 64;
    char* hi_base = B + (size_t)kt * (KCODES * 128) + (size_t)(n >> 7) * 16384;
    char* lo_base = hi_base + (size_t)4 * (KCODES * 128);
    const int row = n & 127;
    const int swz = (row & 7) << 4;
#pragma unroll
    for (int g = 0; g < 8; ++g) {
        const float4 a = *(const float4*)(src + g * 8);
        const float4 c = *(const float4*)(src + g * 8 + 4);
        const float vr[8] = {a.x, a.y, a.z, a.w, c.x, c.y, c.z, c.w};
        unsigned hv[4], lv[4];
#pragma unroll
        for (int e2 = 0; e2 < 4; ++e2) {
            const unsigned short h0 = f2bf(vr[e2 * 2]), h1 = f2bf(vr[e2 * 2 + 1]);
            const unsigned short l0 = f2bf(vr[e2 * 2] - bf2f(h0));
            const unsigned short l1 = f2bf(vr[e2 * 2 + 1] - bf2f(h1));
            hv[e2] = (unsigned)h0 | ((unsigned)h1 << 16);
            lv[e2] = (unsigned)l0 | ((unsigned)l1 << 16);
        }
        const int byte = (row * 128 + g * 16) ^ swz;
        *(uint4*)(hi_base + byte) = make_uint4(hv[0], hv[1], hv[2], hv[3]);
        *(uint4*)(lo_base + byte) = make_uint4(lv[0], lv[1], lv[2], lv[3]);
    }
}

// ---------------- mfma_top2: 128x128 tile GEMM (12 K-subtiles of 64) + fused top-2 ----------------
// 2-phase pipeline (T3 minimum): double-buffered LDS; issue stage(pp+1) BEFORE
// compute(pp); single __syncthreads per step (drains vmcnt+lgkmcnt).
// Grid: nb fast axis -> concurrent blocks share A row-stripe, B stays L2-hot.
__global__ __launch_bounds__(256, 2) void mfma_top2_kernel(
    const char* __restrict__ Ag, const char* __restrict__ Bg,
    const float* __restrict__ esq, float4* __restrict__ top2)
{
    __shared__ char lds[2 * 32768];   // per buf: A tile 16K | B tile 16K
    const int t = threadIdx.x;
    const int w = t >> 6, l = t & 63;
    const int nb = blockIdx.x;    // code-block (fast axis)
    const int mb = blockIdx.y;    // row-block
    const int lh = l >> 4, ll = l & 15;

    int aoff[2][4], boff[2][4];
#pragma unroll
    for (int ks = 0; ks < 2; ++ks)
#pragma unroll
        for (int i = 0; i < 4; ++i) {
            const int ar = (w >> 1) * 64 + i * 16 + ll;
            aoff[ks][i] = (ar * 128 + ks * 64 + lh * 16) ^ ((ar & 7) << 4);
            const int br = (w & 1) * 64 + i * 16 + ll;
            boff[ks][i] = 16384 + ((br * 128 + ks * 64 + lh * 16) ^ ((br & 7) << 4));
        }

    const char* Abase = Ag + (size_t)mb * 16384;
    const char* Bbase = Bg + (size_t)nb * 16384;

    f32x4 acc[4][4];
#pragma unroll
    for (int i = 0; i < 4; ++i)
#pragma unroll
        for (int j = 0; j < 4; ++j) acc[i][j] = 0.f;

    static constexpr int PA[12] = {0, 1, 2, 3, 4, 5, 6, 7, 0, 1, 2, 3};
    static constexpr int PB[12] = {0, 1, 2, 3, 0, 1, 2, 3, 4, 5, 6, 7};

#define STAGE(PP, BUF) do {                                                    \
        const char* At_ = Abase + (size_t)PA[(PP)] * (NROWS * 128);            \
        const char* Bt_ = Bbase + (size_t)PB[(PP)] * (KCODES * 128);           \
        char* dst_ = lds + (BUF) * 32768;                                      \
        _Pragma("unroll")                                                      \
        for (int i_ = 0; i_ < 4; ++i_) {                                       \
            const int g16_ = (i_ * 256 + t) * 16;                              \
            gload_lds16(At_ + g16_, dst_ + g16_);                              \
            gload_lds16(Bt_ + g16_, dst_ + 16384 + g16_);                      \
        }                                                                      \
    } while (0)

    // prologue: stage pp=0 into buf0
    STAGE(0, 0);
    __syncthreads();   // drains vmcnt(0) before barrier

#pragma unroll
    for (int pp = 0; pp < 12; ++pp) {
        const int cur = pp & 1;
        if (pp < 11) STAGE(pp + 1, cur ^ 1);   // issue-early: flies under compute
        const char* lb = lds + cur * 32768;
#pragma unroll
        for (int ks = 0; ks < 2; ++ks) {
            bf16x8 af[4], bfr[4];
#pragma unroll
            for (int i = 0; i < 4; ++i) {
                af[i]  = *(const bf16x8*)(lb + aoff[ks][i]);
                bfr[i] = *(const bf16x8*)(lb + boff[ks][i]);
            }
#pragma unroll
            for (int i = 0; i < 4; ++i)
#pragma unroll
                for (int j = 0; j < 4; ++j)
                    acc[i][j] = __builtin_amdgcn_mfma_f32_16x16x32_bf16(af[i], bfr[j], acc[i][j], 0, 0, 0);
        }
        __syncthreads();   // waits vmcnt(0)+lgkmcnt(0): next buf complete, this buf free
    }
#undef STAGE

    // epilogue: per-row top2 over this wave's 64 cols.
    float b1[16], b2[16];
    int k1[16];
#pragma unroll
    for (int q = 0; q < 16; ++q) { b1[q] = 3.4e38f; b2[q] = 3.4e38f; k1[q] = 0; }
    const int colg0 = nb * 128 + (w & 1) * 64 + ll;
#pragma unroll
    for (int j = 0; j < 4; ++j) {
        const int kcol = colg0 + j * 16;
        const float eq = esq[kcol];
#pragma unroll
        for (int i = 0; i < 4; ++i)
#pragma unroll
            for (int r = 0; r < 4; ++r) {
                const float s = fmaf(-2.f, acc[i][j][r], eq);
                const int q = i * 4 + r;
                if (s < b1[q]) { b2[q] = b1[q]; b1[q] = s; k1[q] = kcol; }
                else if (s < b2[q]) { b2[q] = s; }
            }
    }
#pragma unroll
    for (int msk = 1; msk <= 8; msk <<= 1) {
#pragma unroll
        for (int q = 0; q < 16; ++q) {
            const float ob1 = __shfl_xor(b1[q], msk, 64);
            const int   ok1 = __shfl_xor(k1[q], msk, 64);
            const float ob2 = __shfl_xor(b2[q], msk, 64);
            if (ob1 < b1[q] || (ob1 == b1[q] && ok1 < k1[q])) {
                b2[q] = fminf(b1[q], ob2); b1[q] = ob1; k1[q] = ok1;
            } else {
                b2[q] = fminf(b2[q], ob1);
            }
        }
    }
    if (ll == 0) {
        const size_t cc = (size_t)(nb * 2 + (w & 1)) * NROWS;
#pragma unroll
        for (int q = 0; q < 16; ++q) {
            const int i = q >> 2, r = q & 3;
            const int row = mb * 128 + (w >> 1) * 64 + i * 16 + lh * 4 + r;
            top2[cc + row] = make_float4(b1[q], __int_as_float(k1[q]), b2[q], 0.f);
        }
    }
}

// ---------------- reduce: merge 64 col-chunks per row; compact ambiguous rows ----------------
__global__ __launch_bounds__(256) void reduce_top2_kernel(const float4* __restrict__ top2,
                                                          int* __restrict__ bidx,
                                                          int* __restrict__ flags,
                                                          int* __restrict__ list,
                                                          unsigned long long* __restrict__ res,
                                                          int* __restrict__ cnt) {
    const int row = blockIdx.x * 256 + threadIdx.x;
    float b1 = 3.4e38f, b2 = 3.4e38f;
    int k1 = 0x7fffffff;
#pragma unroll 8
    for (int c = 0; c < 64; ++c) {
        const float4 v = top2[(size_t)c * NROWS + row];
        const float ob1 = v.x, ob2 = v.z;
        const int ok1 = __float_as_int(v.y);
        if (ob1 < b1 || (ob1 == b1 && ok1 < k1)) { b2 = fminf(b1, ob2); b1 = ob1; k1 = ok1; }
        else { b2 = fminf(b2, ob1); }
    }
    bidx[row] = k1;
    const int f = (b2 - b1 <= DELTA) ? 1 : 0;
    flags[row] = f;
    if (f) {
        res[row] = ~0ULL;
        const int slot = atomicAdd(cnt, 1);
        list[slot] = row;
    }
}

// ---------------- rescore8: exact fp32 rescore, 8 rows x 256-code chunk per block ----------------
__global__ __launch_bounds__(256) void rescore8_kernel(const float* __restrict__ x,
                                                       const float* __restrict__ emb,
                                                       const float* __restrict__ esq,
                                                       const int* __restrict__ list,
                                                       const int* __restrict__ cnt,
                                                       unsigned long long* __restrict__ res) {
    __shared__ float xs[8][CCH];
    __shared__ int rid[8];
    const int t = threadIdx.x;
    const int q = blockIdx.x & 15;            // code chunk
    const int eg = blockIdx.x >> 4;           // entry group
    const int count = *cnt;
    const int k = q * 256 + t;
    const float eq = esq[k];
    const float* ek = emb + (size_t)k * CCH;

    for (int e8 = eg * 8; e8 < count; e8 += 128 * 8) {
        if (t < 8) rid[t] = (e8 + t < count) ? list[e8 + t] : -1;
        __syncthreads();
#pragma unroll
        for (int r = 0; r < 8; ++r) {
            const int rr = rid[r];
            if (rr >= 0) {
                const int b = rr >> 10, p = rr & 1023;
                xs[r][t] = x[((size_t)b * CCH + t) * N_PIX + p];
            }
        }
        __syncthreads();

        float dot[8];
#pragma unroll
        for (int r = 0; r < 8; ++r) dot[r] = 0.f;
#pragma unroll 8
        for (int c4 = 0; c4 < 64; ++c4) {
            const float4 e4 = *(const float4*)(ek + c4 * 4);
#pragma unroll
            for (int r = 0; r < 8; ++r) {
                const float4 xv = *(const float4*)(&xs[r][c4 * 4]);
                dot[r] = fmaf(xv.x, e4.x, dot[r]);
                dot[r] = fmaf(xv.y, e4.y, dot[r]);
                dot[r] = fmaf(xv.z, e4.z, dot[r]);
                dot[r] = fmaf(xv.w, e4.w, dot[r]);
            }
        }
#pragma unroll
        for (int r = 0; r < 8; ++r) {
            const float s = fmaf(-2.f, dot[r], eq);
            unsigned long long key = (((unsigned long long)mono(s)) << 32) | (unsigned)k;
#pragma unroll
            for (int off = 32; off > 0; off >>= 1) {
                const unsigned long long ok = __shfl_xor(key, off, 64);
                if (ok < key) key = ok;
            }
            if ((t & 63) == 0 && rid[r] >= 0)
                atomicMin(&res[rid[r]], key);
        }
        __syncthreads();
    }
}

// ---------------- apply: copy resolved indices for flagged rows ----------------
__global__ __launch_bounds__(256) void apply_kernel(const int* __restrict__ flags,
                                                    const unsigned long long* __restrict__ res,
                                                    int* __restrict__ bidx) {
    const int row = blockIdx.x * 256 + threadIdx.x;
    if (flags[row]) bidx[row] = (int)(res[row] & 0xFFFFFFFFULL);
}

// ---------------- fallback fp32 argmin (known-good) if ws too small ----------------
#define BROWS 32
#define FKTILE 256
#define FDCH 16
__global__ __launch_bounds__(256, 2) void argmin_fb_kernel(
    const float* __restrict__ x, const float* __restrict__ emb,
    const float* __restrict__ esq, int* __restrict__ bidx)
{
    __shared__ float xs[CCH * BROWS];
    __shared__ float es[FDCH * FKTILE];
    const int t = threadIdx.x;
    const int w = t >> 6;
    const int l = t & 63;
    const int n0 = blockIdx.x * BROWS;
    const int b = n0 >> 10;
    const int pixbase = n0 & (N_PIX - 1);
    const float* xb = x + (size_t)b * CCH * N_PIX + pixbase;
    {
        const int p4 = (t & 7) * 4;
        const int crow = t >> 3;
#pragma unroll
        for (int i = 0; i < 8; ++i) {
            const int c = i * 32 + crow;
            *(float4*)(xs + c * BROWS + p4) = *(const float4*)(xb + (size_t)c * N_PIX + p4);
        }
    }
    float best[8]; int bk[8];
#pragma unroll
    for (int r = 0; r < 8; ++r) { best[r] = 3.4e38f; bk[r] = 0; }
    float acc[8][4];
#pragma unroll
    for (int r = 0; r < 8; ++r)
#pragma unroll
        for (int j = 0; j < 4; ++j) acc[r][j] = 0.f;
    for (int kt = 0; kt < KCODES / FKTILE; ++kt) {
        for (int dc = 0; dc < CCH / FDCH; ++dc) {
            __syncthreads();
            {
                const float* src = emb + (size_t)(kt * FKTILE + t) * CCH + dc * FDCH;
#pragma unroll
                for (int c = 0; c < FDCH; ++c) es[c * FKTILE + t] = src[c];
            }
            __syncthreads();
            const int c0 = dc * FDCH;
            const float* ep = es + 4 * l;
            const float* xp = xs + c0 * BROWS + w * 8;
#pragma unroll
            for (int c = 0; c < FDCH; ++c) {
                const float4 ev = *(const float4*)(ep + c * FKTILE);
                const float4 xa = *(const float4*)(xp + c * BROWS);
                const float4 xc = *(const float4*)(xp + c * BROWS + 4);
                const float xr8[8] = {xa.x, xa.y, xa.z, xa.w, xc.x, xc.y, xc.z, xc.w};
#pragma unroll
                for (int r = 0; r < 8; ++r) {
                    acc[r][0] = fmaf(xr8[r], ev.x, acc[r][0]);
                    acc[r][1] = fmaf(xr8[r], ev.y, acc[r][1]);
                    acc[r][2] = fmaf(xr8[r], ev.z, acc[r][2]);
                    acc[r][3] = fmaf(xr8[r], ev.w, acc[r][3]);
                }
            }
        }
        const float4 q = *(const float4*)(esq + kt * FKTILE + 4 * l);
        const float qr[4] = {q.x, q.y, q.z, q.w};
#pragma unroll
        for (int r = 0; r < 8; ++r)
#pragma unroll
            for (int j = 0; j < 4; ++j) {
                const float s = fmaf(-2.f, acc[r][j], qr[j]);
                if (s < best[r]) { best[r] = s; bk[r] = kt * FKTILE + 4 * l + j; }
                acc[r][j] = 0.f;
            }
    }
#pragma unroll
    for (int r = 0; r < 8; ++r) {
        float bv = best[r]; int bi = bk[r];
#pragma unroll
        for (int off = 32; off > 0; off >>= 1) {
            const float ov = __shfl_xor(bv, off, 64);
            const int   oi = __shfl_xor(bi, off, 64);
            if (ov < bv || (ov == bv && oi < bi)) { bv = ov; bi = oi; }
        }
        if (l == 0) bidx[n0 + w * 8 + r] = bi;
    }
}

// ---------------- gather + oup + loss partials ----------------
__global__ __launch_bounds__(256) void gather_kernel(
    const float* __restrict__ x, const float* __restrict__ emb,
    const int* __restrict__ bidx, float* __restrict__ oup,
    float* __restrict__ partial)
{
    __shared__ int sidx[64];
    __shared__ float red[256];
    const int t = threadIdx.x;
    const int n0 = blockIdx.x * 64;
    const int b = n0 >> 10;
    const int pixbase = n0 & (N_PIX - 1);
    if (t < 64) sidx[t] = bidx[n0 + t];
    __syncthreads();
    const int pl = t & 63;
    const int w = t >> 6;
    const int k = sidx[pl];
    const float* xbp = x + (size_t)b * CCH * N_PIX + pixbase + pl;
    float* ob = oup + (size_t)b * CCH * N_PIX + pixbase + pl;
    const float* ek = emb + (size_t)k * CCH + w * 64;
    float lsum = 0.f;
#pragma unroll 4
    for (int cc = 0; cc < 16; ++cc) {
        const float4 e4 = *(const float4*)(ek + cc * 4);
        const float er[4] = {e4.x, e4.y, e4.z, e4.w};
#pragma unroll
        for (int j = 0; j < 4; ++j) {
            const size_t off = (size_t)(w * 64 + cc * 4 + j) * N_PIX;
            const float xv = xbp[off];
            ob[off] = er[j];
            const float d = xv - er[j];
            lsum = fmaf(d, d, lsum);
        }
    }
    red[t] = lsum;
    __syncthreads();
#pragma unroll
    for (int s = 128; s > 0; s >>= 1) {
        if (t < s) red[t] += red[t + s];
        __syncthreads();
    }
    if (t == 0) partial[blockIdx.x] = red[0];
}

__global__ __launch_bounds__(256) void finalize_kernel(const float* __restrict__ partial,
                                                       float* __restrict__ out_losses) {
    __shared__ float red[256];
    const int t = threadIdx.x;
    red[t] = partial[t] + partial[t + 256];
    __syncthreads();
    for (int s = 128; s > 0; s >>= 1) {
        if (t < s) red[t] += red[t + s];
        __syncthreads();
    }
    if (t == 0) {
        const float loss = red[0] * (1.0f / 8388608.0f);
        out_losses[0] = loss;
        out_losses[1] = loss;
    }
}

extern "C" void kernel_launch(void* const* d_in, const int* in_sizes, int n_in,
                              void* d_out, int out_size, void* d_ws, size_t ws_size,
                              hipStream_t stream) {
    const float* x = (const float*)d_in[0];
    const float* emb = (const float*)d_in[1];
    float* out = (float*)d_out;

    char* ws = (char*)d_ws;
    float* esq = (float*)(ws + OFF_ESQ);
    int* bidx = (int*)(ws + OFF_BIDX);
    int* flags = (int*)(ws + OFF_FLAGS);
    float* partial = (float*)(ws + OFF_PART);

    esq_kernel<<<KCODES / 4, 256, 0, stream>>>(emb, esq);

    if (ws_size >= (size_t)WS_NEEDED) {
        float4* top2 = (float4*)(ws + OFF_TOP2);
        char* A = ws + OFF_A;
        char* B = ws + OFF_B;
        int* list = (int*)(ws + OFF_LIST);
        unsigned long long* res = (unsigned long long*)(ws + OFF_RES);
        int* cnt = (int*)(ws + OFF_CNT);
        conv_x_kernel<<<NROWS / 64, 256, 0, stream>>>(x, A);
        conv_e_kernel<<<KCODES / 64, 256, 0, stream>>>(emb, B, cnt);
        mfma_top2_kernel<<<dim3(KCODES / 128, NROWS / 128), 256, 0, stream>>>(A, B, esq, top2);
        reduce_top2_kernel<<<NROWS / 256, 256, 0, stream>>>(top2, bidx, flags, list, res, cnt);
        rescore8_kernel<<<2048, 256, 0, stream>>>(x, emb, esq, list, cnt, res);
        apply_kernel<<<NROWS / 256, 256, 0, stream>>>(flags, res, bidx);
    } else {
        argmin_fb_kernel<<<NROWS / BROWS, 256, 0, stream>>>(x, emb, esq, bidx);
    }

    gather_kernel<<<NROWS / 64, 256, 0, stream>>>(x, emb, bidx, out, partial);
    finalize_kernel<<<1, 256, 0, stream>>>(partial, out + 8388608);
}